// Round 10
// baseline (2090.739 us; speedup 1.0000x reference)
//
#include <hip/hip_runtime.h>
#include <hip/hip_bf16.h>
#include <hip/hip_cooperative_groups.h>
#include <math.h>

namespace cg = cooperative_groups;

#define BB 2
#define NN 2048
#define HH 256
#define WW 256
#define CC 128
#define YSTR 1048576   // elements per Y partial ([4096][256])

typedef __hip_bfloat16 bf16;
typedef short short8 __attribute__((ext_vector_type(8)));
typedef float f32x4 __attribute__((ext_vector_type(4)));
typedef unsigned short ushort4v __attribute__((ext_vector_type(4)));

__device__ inline float bf2f(unsigned short u) {
    return __uint_as_float(((unsigned int)u) << 16);
}
__device__ inline unsigned short f2bf_bits(float f) {
    __hip_bfloat16 h = __float2bfloat16(f);
    return *reinterpret_cast<unsigned short*>(&h);
}

// ================= prep phase: conv (grid-strided) + interp + weight transpose =================
__device__ __forceinline__ void prep_phase(char* lds, int bid, int tid,
        const float* __restrict__ adj, bf16* __restrict__ adjB,
        const float* __restrict__ features, const float* __restrict__ base_point,
        bf16* __restrict__ x0p,
        const float* __restrict__ w_first, const float* __restrict__ w_mid,
        const float* __restrict__ w_last, bf16* __restrict__ wT) {
    #pragma unroll
    for (int i = 0; i < 4; ++i) {
        size_t base = ((size_t)(i * 512 + bid) * 256 + tid) * 16;
        #pragma unroll
        for (int h = 0; h < 2; ++h) {
            float4 f0 = *(const float4*)(adj + base + h * 8);
            float4 f1 = *(const float4*)(adj + base + h * 8 + 4);
            short8 v;
            v[0] = (short)f2bf_bits(f0.x); v[1] = (short)f2bf_bits(f0.y);
            v[2] = (short)f2bf_bits(f0.z); v[3] = (short)f2bf_bits(f0.w);
            v[4] = (short)f2bf_bits(f1.x); v[5] = (short)f2bf_bits(f1.y);
            v[6] = (short)f2bf_bits(f1.z); v[7] = (short)f2bf_bits(f1.w);
            *(short8*)(adjB + base + h * 8) = v;
        }
    }
    {
        int w = tid >> 6, lane = tid & 63;
        #pragma unroll
        for (int rep = 0; rep < 2; ++rep) {
            int idx = bid * 4 + w + rep * 2048;     // 0..4095
            int b = idx >> 11;
            float bx = base_point[idx * 2 + 0];
            float by = base_point[idx * 2 + 1];
            float xs = bx * (float)WW;
            float ys = by * (float)HH;
            float x0f = floorf(xs), y0f = floorf(ys);
            float x1f = x0f + 1.f, y1f = y0f + 1.f;
            float w00 = (x1f - xs) * (y1f - ys);
            float w01 = (x1f - xs) * (ys - y0f);
            float w10 = (xs - x0f) * (y1f - ys);
            float w11 = (xs - x0f) * (ys - y0f);
            int X0 = (int)fminf(fmaxf(x0f, 0.f), (float)(WW - 1));
            int X1 = (int)fminf(fmaxf(x1f, 0.f), (float)(WW - 1));
            int Y0 = (int)fminf(fmaxf(y0f, 0.f), (float)(HH - 1));
            int Y1 = (int)fminf(fmaxf(y1f, 0.f), (float)(HH - 1));
            int p00 = Y0 * WW + X0, p01 = Y1 * WW + X0;
            int p10 = Y0 * WW + X1, p11 = Y1 * WW + X1;
            int c0 = lane * 2;
            const float* f0 = features + (size_t)(b * CC + c0) * (HH * WW);
            const float* f1 = f0 + HH * WW;
            float v0 = w00 * f0[p00] + w01 * f0[p01] + w10 * f0[p10] + w11 * f0[p11];
            float v1 = w00 * f1[p00] + w01 * f1[p01] + w10 * f1[p10] + w11 * f1[p11];
            unsigned int pk = (unsigned int)f2bf_bits(v0) | ((unsigned int)f2bf_bits(v1) << 16);
            *(unsigned int*)(x0p + (size_t)idx * 256 + c0) = pk;
            unsigned int pk2 = 0;
            if (lane == 0)
                pk2 = (unsigned int)f2bf_bits(bx) | ((unsigned int)f2bf_bits(by) << 16);
            *(unsigned int*)(x0p + (size_t)idx * 256 + 128 + c0) = pk2;
        }
    }
    {
        float (*tbuf)[33] = (float(*)[33])lds;
        for (int i = 0; i < 4; ++i) {
            int u = bid + i * 512;
            if (u < 1792) {
                int m = u >> 6;
                int sub = u & 63;
                int bx = sub & 7, by = sub >> 3;
                const float* S; int R;
                if (m < 2)       { S = w_first + (size_t)m * 130 * 256; R = 130; }
                else if (m < 26) { S = w_mid + (size_t)(m - 2) * 65536; R = 256; }
                else             { S = w_last + (size_t)(m - 26) * 65536; R = 256; }
                bf16* D = wT + (size_t)m * 65536;
                int tx = tid & 31, ty = tid >> 5;
                int c0 = bx * 32, r0 = by * 32;
                #pragma unroll
                for (int k = 0; k < 4; ++k) {
                    int r = r0 + ty + 8 * k;
                    tbuf[ty + 8 * k][tx] = (r < R) ? S[(size_t)r * 256 + c0 + tx] : 0.f;
                }
                __syncthreads();
                #pragma unroll
                for (int k = 0; k < 4; ++k) {
                    int c = c0 + ty + 8 * k;
                    D[(size_t)c * 256 + r0 + tx] = __float2bfloat16(tbuf[tx][ty + 8 * k]);
                }
            }
            __syncthreads();
        }
    }
}

// ================= S phase: x = combine(gprev + Y0..1 + b1 + b2 [+res][relu]) ; [g1|g2T] = x @ wcat =================
// 32 KB LDS: B dbuf 2x8 KB @0 (64-outfeat x 64K sub-tiles), Al 16 KB @16384 (4 planes x 32 rows).
__device__ __forceinline__ void s_phase(char* lds, int bid, int tid,
        const bf16* __restrict__ gprev, const bf16* __restrict__ Yb2,
        const float* __restrict__ bias1, const float* __restrict__ bias2,
        const bf16* __restrict__ res, int relu,
        const bf16* __restrict__ wcat,
        bf16* __restrict__ xR, bf16* __restrict__ g1out, bf16* __restrict__ g2T) {
    int lin = (bid & 7) * 64 + (bid >> 3);
    int ct = lin & 3, rt = lin >> 2;
    int lane = tid & 63, w = tid >> 6;
    int wr = w >> 1, wc = w & 1;       // wave: 16 rows x 32 outfeats (per sub-stage)
    int row16 = lane & 15, kg = lane >> 4;
    char* Al = lds + 16384;

    #define S_STAGE(BUF, PLANE, HALF)                                                     \
        _Pragma("unroll")                                                                 \
        for (int rnd = 0; rnd < 2; ++rnd) {                                               \
            int dp = rnd * 4096 + tid * 16;                                               \
            int row = dp >> 7;                                                            \
            int cb = dp & 127;                                                            \
            int sc = (cb ^ ((row & 7) << 4)) >> 1;                                        \
            __builtin_amdgcn_global_load_lds(                                             \
                (const __attribute__((address_space(1))) void*)(wcat + (size_t)(ct * 128 + (HALF) * 64 + row) * 256 + (PLANE) * 64 + sc), \
                (__attribute__((address_space(3))) void*)(lds + (BUF) * 8192 + rnd * 4096 + (w << 10)), \
                16, 0, 0);                                                                \
        }

    S_STAGE(0, 0, 0);

    // ---- A combine: 4 planes -> Al (swizzled ds_write) ----
    {
        int arw = tid >> 3;                 // 0..31
        int acb = (tid * 16) & 127;
        int ridx = rt * 32 + arw;
        int awb = arw * 128 + (acb ^ ((arw & 7) << 4));
        #pragma unroll
        for (int rnd = 0; rnd < 4; ++rnd) {
            int gcol = rnd * 64 + (acb >> 1);
            size_t off = (size_t)ridx * 256 + gcol;
            short8 pk;
            if (Yb2) {
                short8 gv = *(const short8*)(gprev + off);
                short8 y0v = *(const short8*)(Yb2 + off);
                short8 y1v = *(const short8*)(Yb2 + YSTR + off);
                short8 rv = {};
                if (res) rv = *(const short8*)(res + off);
                #pragma unroll
                for (int j = 0; j < 8; ++j) {
                    float f = bf2f((unsigned short)gv[j]) + bf2f((unsigned short)y0v[j])
                            + bf2f((unsigned short)y1v[j])
                            + bias1[gcol + j] + bias2[gcol + j];
                    if (res)  f += bf2f((unsigned short)rv[j]);
                    if (relu) f = fmaxf(f, 0.f);
                    pk[j] = (short)f2bf_bits(f);
                }
            } else {
                pk = *(const short8*)(gprev + off);
            }
            if (ct == 0) *(short8*)(xR + off) = pk;
            *(short8*)(Al + rnd * 4096 + awb) = pk;
        }
    }

    asm volatile("s_waitcnt vmcnt(0) lgkmcnt(0)" ::: "memory");
    __builtin_amdgcn_s_barrier();

    f32x4 acc[2][2] = {};
    int arow = wr * 16 + row16;

    #define S_MFMA(BUF, PLANE, H)                                                         \
        _Pragma("unroll")                                                                 \
        for (int kk = 0; kk < 2; ++kk) {                                                  \
            int kof = kk * 64 + kg * 16;                                                  \
            short8 a = *(const short8*)(Al + (PLANE) * 4096 + arow * 128 + (kof ^ ((arow & 7) << 4))); \
            _Pragma("unroll")                                                             \
            for (int nf = 0; nf < 2; ++nf) {                                              \
                int fr = wc * 32 + nf * 16 + row16;                                       \
                short8 bfr = *(const short8*)(lds + (BUF) * 8192 + fr * 128 + (kof ^ ((fr & 7) << 4))); \
                acc[H][nf] = __builtin_amdgcn_mfma_f32_16x16x32_bf16(a, bfr, acc[H][nf], 0, 0, 0); \
            }                                                                             \
        }

    #define S_ITER(CUR, CP, CH, NXT, NP, NH)                                              \
        S_STAGE(NXT, NP, NH);                                                             \
        asm volatile("s_waitcnt vmcnt(2)" ::: "memory");                                  \
        __builtin_amdgcn_s_barrier();                                                     \
        S_MFMA(CUR, CP, CH);                                                              \
        __builtin_amdgcn_s_barrier();

    S_ITER(0, 0, 0, 1, 0, 1)
    S_ITER(1, 0, 1, 0, 1, 0)
    S_ITER(0, 1, 0, 1, 1, 1)
    S_ITER(1, 1, 1, 0, 2, 0)
    S_ITER(0, 2, 0, 1, 2, 1)
    S_ITER(1, 2, 1, 0, 3, 0)
    S_ITER(0, 3, 0, 1, 3, 1)
    asm volatile("s_waitcnt vmcnt(0)" ::: "memory");
    __builtin_amdgcn_s_barrier();
    S_MFMA(1, 3, 1);

    int rb = rt * 32 + wr * 16 + kg * 4;
    #pragma unroll
    for (int h = 0; h < 2; ++h) {
        #pragma unroll
        for (int nf = 0; nf < 2; ++nf) {
            int c = ct * 128 + h * 64 + wc * 32 + nf * 16 + row16;
            if (c < 256) {
                #pragma unroll
                for (int j = 0; j < 4; ++j)
                    *reinterpret_cast<unsigned short*>(&g1out[(size_t)(rb + j) * 256 + c]) = f2bf_bits(acc[h][nf][j]);
            } else {
                int c2 = c - 256;
                ushort4v pk;
                #pragma unroll
                for (int j = 0; j < 4; ++j) pk[j] = f2bf_bits(acc[h][nf][j]);
                *(ushort4v*)(g2T + (size_t)c2 * 4096 + rb) = pk;
            }
        }
    }
    #undef S_STAGE
    #undef S_MFMA
    #undef S_ITER
}

// ================= B phase: Y[kh] = adj[:, kh half] @ g2 — BM=64, BN=64, BK=64, split-K=2 =================
// 32 KB LDS: buf i @ i*16384 (A 8 KB + B 8 KB @ +8192). counted vmcnt(4) double-buffer, 16 K-iters.
__device__ __forceinline__ void b_phase(char* lds, int bid, int tid,
        const bf16* __restrict__ adjB, const bf16* __restrict__ g2T,
        bf16* __restrict__ Ybase) {
    int lin = (bid & 7) * 64 + (bid >> 3);
    int ct = lin & 3, rt = (lin >> 2) & 31, z = lin >> 7;
    int b = z >> 1, kh = z & 1;
    const bf16* Aadj = adjB + (size_t)b * NN * NN + (size_t)(rt * 64) * NN + kh * 1024;
    const bf16* Bg   = g2T + (size_t)(ct * 64) * 4096 + b * NN + kh * 1024;
    bf16* Yo = Ybase + (size_t)kh * YSTR;
    int lane = tid & 63, w = tid >> 6;
    int wr = w >> 1, wc = w & 1;       // wave tile: 32 rows x 32 cols
    int row16 = lane & 15, kg = lane >> 4;
    f32x4 acc[2][2] = {};

    #define B_STAGE(BUF, IT)                                                              \
        {                                                                                 \
            int k0 = (IT) * 64;                                                           \
            _Pragma("unroll")                                                             \
            for (int rnd = 0; rnd < 2; ++rnd) {                                           \
                int d = tid * 16 + rnd * 4096;                                            \
                int row = d >> 7, cb = d & 127;                                           \
                int sc = (cb ^ ((row & 7) << 4)) >> 1;                                    \
                __builtin_amdgcn_global_load_lds(                                         \
                    (const __attribute__((address_space(1))) void*)(Aadj + (size_t)row * NN + k0 + sc), \
                    (__attribute__((address_space(3))) void*)(lds + (BUF) * 16384 + rnd * 4096 + (w << 10)), \
                    16, 0, 0);                                                            \
            }                                                                             \
            _Pragma("unroll")                                                             \
            for (int rnd = 0; rnd < 2; ++rnd) {                                           \
                int d = tid * 16 + rnd * 4096;                                            \
                int row = d >> 7, cb = d & 127;                                           \
                int sc = (cb ^ ((row & 7) << 4)) >> 1;                                    \
                __builtin_amdgcn_global_load_lds(                                         \
                    (const __attribute__((address_space(1))) void*)(Bg + (size_t)row * 4096 + k0 + sc), \
                    (__attribute__((address_space(3))) void*)(lds + (BUF) * 16384 + 8192 + rnd * 4096 + (w << 10)), \
                    16, 0, 0);                                                            \
            }                                                                             \
        }

    #define B_MFMA(BUF)                                                                   \
        _Pragma("unroll")                                                                 \
        for (int kk = 0; kk < 2; ++kk) {                                                  \
            short8 a[2], bfr[2];                                                          \
            _Pragma("unroll")                                                             \
            for (int mf = 0; mf < 2; ++mf) {                                              \
                int row = wr * 32 + mf * 16 + row16;                                      \
                a[mf] = *(const short8*)(lds + (BUF) * 16384 + row * 128 +                \
                          (((kk * 64) + kg * 16) ^ ((row & 7) << 4)));                    \
            }                                                                             \
            _Pragma("unroll")                                                             \
            for (int nf = 0; nf < 2; ++nf) {                                              \
                int fr = wc * 32 + nf * 16 + row16;                                       \
                bfr[nf] = *(const short8*)(lds + (BUF) * 16384 + 8192 + fr * 128 +        \
                          (((kk * 64) + kg * 16) ^ ((fr & 7) << 4)));                     \
            }                                                                             \
            _Pragma("unroll")                                                             \
            for (int mf = 0; mf < 2; ++mf)                                                \
                _Pragma("unroll")                                                         \
                for (int nf = 0; nf < 2; ++nf)                                            \
                    acc[mf][nf] = __builtin_amdgcn_mfma_f32_16x16x32_bf16(a[mf], bfr[nf], acc[mf][nf], 0, 0, 0); \
        }

    #define B_ITER(CUR, NXT, IT)                                                          \
        B_STAGE(NXT, IT);                                                                 \
        asm volatile("s_waitcnt vmcnt(4)" ::: "memory");                                  \
        __builtin_amdgcn_s_barrier();                                                     \
        B_MFMA(CUR);                                                                      \
        __builtin_amdgcn_s_barrier();

    B_STAGE(0, 0);
    B_ITER(0, 1, 1)
    B_ITER(1, 0, 2)
    B_ITER(0, 1, 3)
    B_ITER(1, 0, 4)
    B_ITER(0, 1, 5)
    B_ITER(1, 0, 6)
    B_ITER(0, 1, 7)
    B_ITER(1, 0, 8)
    B_ITER(0, 1, 9)
    B_ITER(1, 0, 10)
    B_ITER(0, 1, 11)
    B_ITER(1, 0, 12)
    B_ITER(0, 1, 13)
    B_ITER(1, 0, 14)
    B_ITER(0, 1, 15)
    asm volatile("s_waitcnt vmcnt(0)" ::: "memory");
    __builtin_amdgcn_s_barrier();
    B_MFMA(1);

    #pragma unroll
    for (int mf = 0; mf < 2; ++mf) {
        #pragma unroll
        for (int nf = 0; nf < 2; ++nf) {
            int c  = ct * 64 + wc * 32 + nf * 16 + row16;
            int r0 = b * NN + rt * 64 + wr * 32 + mf * 16 + kg * 4;
            #pragma unroll
            for (int j = 0; j < 4; ++j)
                *reinterpret_cast<unsigned short*>(&Yo[(size_t)(r0 + j) * 256 + c]) = f2bf_bits(acc[mf][nf][j]);
        }
    }
    #undef B_STAGE
    #undef B_MFMA
    #undef B_ITER
}

// ================= head + lap phases =================
__device__ __forceinline__ void head_phase(int bid, int tid,
        const bf16* __restrict__ g1, const bf16* __restrict__ Yb2,
        const float* __restrict__ b_last, const float* __restrict__ w_fc,
        const float* __restrict__ b_fc, const float* __restrict__ base_point,
        const float* __restrict__ point_mask, float* __restrict__ out,
        float* __restrict__ dpts) {
    if (bid == 0 && tid < 2)
        out[4 * BB * NN + tid] = 0.f;
    int r = bid * 8 + (tid >> 5);
    int qq = tid & 31;
    size_t off = (size_t)r * 256 + qq * 8;
    short8 a = *(const short8*)(g1 + off);
    short8 y0v = *(const short8*)(Yb2 + off);
    short8 y1v = *(const short8*)(Yb2 + YSTR + off);
    float s0 = 0.f, s1 = 0.f;
    int d0 = qq * 8;
    #pragma unroll
    for (int j = 0; j < 8; ++j) {
        float z = bf2f((unsigned short)a[j]) + bf2f((unsigned short)y0v[j])
                + bf2f((unsigned short)y1v[j])
                + b_last[d0 + j] + b_last[256 + d0 + j];
        s0 += z * w_fc[(d0 + j) * 2 + 0];
        s1 += z * w_fc[(d0 + j) * 2 + 1];
    }
    #pragma unroll
    for (int o = 16; o; o >>= 1) {
        s0 += __shfl_xor(s0, o);
        s1 += __shfl_xor(s1, o);
    }
    if (qq == 0) {
        s0 += b_fc[0];
        s1 += b_fc[1];
        float m  = point_mask[r];
        float p0 = base_point[r * 2 + 0] + s0 * m;
        float p1 = base_point[r * 2 + 1] + s1 * m;
        out[r * 2 + 0] = p0;
        out[r * 2 + 1] = p1;
        out[2 * BB * NN + r * 2 + 0] = s0;
        out[2 * BB * NN + r * 2 + 1] = s1;
        dpts[r * 2 + 0] = s0 * m;
        dpts[r * 2 + 1] = s1 * m;
    }
}

__device__ __forceinline__ void lap_phase(char* lds, int bid, int tid,
        const bf16* __restrict__ adjB, const float* __restrict__ dpts,
        float* __restrict__ outlap) {
    float* sd = (float*)lds;
    int w = tid >> 6, lane = tid & 63;
    #pragma unroll
    for (int rep = 0; rep < 2; ++rep) {
        int row = bid * 4 + w + rep * 2048;
        int b = row >> 11, n = row & 2047;
        const bf16* ar = adjB + (size_t)b * NN * NN + (size_t)n * NN;
        const float* db = dpts + (size_t)b * NN * 2;
        float s0 = 0.f, s1 = 0.f;
        #pragma unroll
        for (int k4 = 0; k4 < 4; ++k4) {
            int kk = k4 * 512 + lane * 8;
            short8 av = *(const short8*)(ar + kk);
            #pragma unroll
            for (int j = 0; j < 8; ++j) {
                float a = bf2f((unsigned short)av[j]);
                float2 dv = *(const float2*)(db + (kk + j) * 2);
                s0 += a * dv.x;
                s1 += a * dv.y;
            }
        }
        #pragma unroll
        for (int o = 32; o; o >>= 1) {
            s0 += __shfl_xor(s0, o);
            s1 += __shfl_xor(s1, o);
        }
        if (lane == 0) {
            float e0 = dpts[(size_t)row * 2 + 0] - s0;
            float e1 = dpts[(size_t)row * 2 + 1] - s1;
            sd[w] = sqrtf(e0 * e0 + e1 * e1 + 1e-10f);
        }
        __syncthreads();
        if (tid == 0) {
            float s = (sd[0] + sd[1] + sd[2] + sd[3]) * (1.f / (float)NN);
            atomicAdd(&outlap[b], s);
        }
        __syncthreads();
    }
}

// ================= layer bookkeeping (shared host/device logic baked in) =================
struct LayerPtrs {
    const bf16* gprev; const bf16* Ybp;
    const float *bb1, *bb2; const bf16* resp;
    bf16* xw; bf16* g1o; int rl;
};

__host__ __device__ inline LayerPtrs layer_ptrs(int k, char* W,
        const float* b_first, const float* b_mid) {
    bf16* x0p  = (bf16*)(W + 20447232);
    bf16* g1b0 = (bf16*)(W + 22544384);
    bf16* g1b1 = (bf16*)(W + 24641536);
    bf16* Yb   = (bf16*)(W + 28835840);
    bf16* xsl0 = (bf16*)(W + 45613056);
    bf16* xsl1 = (bf16*)(W + 47710208);
    bf16* xscr = (bf16*)(W + 49807360);
    LayerPtrs L;
    L.resp = nullptr; L.rl = 0; L.bb1 = nullptr; L.bb2 = nullptr;
    if (k == 0) {
        L.gprev = x0p; L.Ybp = nullptr; L.xw = xscr;
    } else {
        L.Ybp = Yb;
        L.gprev = ((k - 1) & 1) ? g1b1 : g1b0;
        if (k == 1) {
            L.bb1 = b_first; L.bb2 = b_first + 256; L.rl = 0; L.xw = xsl0;
        } else if ((k & 1) == 0) {
            int m = (k - 2) >> 1;
            L.bb1 = b_mid + (size_t)m * 1024; L.bb2 = L.bb1 + 256; L.rl = 1; L.xw = xscr;
        } else {
            int m = (k - 3) >> 1;
            L.bb1 = b_mid + (size_t)m * 1024 + 512; L.bb2 = L.bb1 + 256; L.rl = 1;
            L.resp = (m & 1) ? xsl1 : xsl0;
            L.xw = (((k - 1) >> 1) & 1) ? xsl1 : xsl0;
        }
    }
    L.g1o = (k & 1) ? g1b1 : g1b0;
    return L;
}

// ================= cooperative fused kernel =================
__global__ __launch_bounds__(256, 2) void fused_kernel(
    const float* __restrict__ adj, const float* __restrict__ features,
    const float* __restrict__ base_point, const float* __restrict__ point_mask,
    const float* __restrict__ w_first, const float* __restrict__ b_first,
    const float* __restrict__ w_mid, const float* __restrict__ b_mid,
    const float* __restrict__ w_last, const float* __restrict__ b_last,
    const float* __restrict__ w_fc, const float* __restrict__ b_fc,
    float* __restrict__ out, char* __restrict__ W) {
    __shared__ char lds[32768];
    cg::grid_group grid = cg::this_grid();
    int bid = blockIdx.x, tid = threadIdx.x;

    bf16* adjB = (bf16*)W;
    bf16* wT   = (bf16*)(W + 16777216);
    bf16* x0p  = (bf16*)(W + 20447232);
    bf16* g1b1 = (bf16*)(W + 24641536);
    bf16* g2T  = (bf16*)(W + 26738688);
    bf16* Yb   = (bf16*)(W + 28835840);
    float* dpts = (float*)(W + 51904512);

    prep_phase(lds, bid, tid, adj, adjB, features, base_point, x0p,
               w_first, w_mid, w_last, wT);
    grid.sync();

    for (int k = 0; k < 14; ++k) {
        LayerPtrs L = layer_ptrs(k, W, b_first, b_mid);
        s_phase(lds, bid, tid, L.gprev, L.Ybp, L.bb1, L.bb2, L.resp, L.rl,
                wT + (size_t)2 * k * 65536, L.xw, L.g1o, g2T);
        grid.sync();
        b_phase(lds, bid, tid, adjB, g2T, Yb);
        grid.sync();
    }

    head_phase(bid, tid, g1b1, Yb, b_last, w_fc, b_fc, base_point, point_mask, out, dpts);
    grid.sync();
    lap_phase(lds, bid, tid, adjB, dpts, out + 4 * BB * NN);
}

// ================= fallback wrapper kernels (same phases, discrete dispatches) =================
__global__ __launch_bounds__(256, 2) void prep_wrap(
    const float* adj, bf16* adjB, const float* features, const float* base_point,
    bf16* x0p, const float* w_first, const float* w_mid, const float* w_last, bf16* wT) {
    __shared__ char lds[32768];
    prep_phase(lds, blockIdx.x, threadIdx.x, adj, adjB, features, base_point, x0p,
               w_first, w_mid, w_last, wT);
}

__global__ __launch_bounds__(256, 2) void s_wrap(
    const bf16* gprev, const bf16* Yb2, const float* bias1, const float* bias2,
    const bf16* res, int relu, const bf16* wcat, bf16* xR, bf16* g1out, bf16* g2T) {
    __shared__ char lds[32768];
    s_phase(lds, blockIdx.x, threadIdx.x, gprev, Yb2, bias1, bias2, res, relu,
            wcat, xR, g1out, g2T);
}

__global__ __launch_bounds__(256, 2) void b_wrap(const bf16* adjB, const bf16* g2T, bf16* Yb) {
    __shared__ char lds[32768];
    b_phase(lds, blockIdx.x, threadIdx.x, adjB, g2T, Yb);
}

__global__ __launch_bounds__(256, 2) void head_wrap(
    const bf16* g1, const bf16* Yb2, const float* b_last, const float* w_fc,
    const float* b_fc, const float* base_point, const float* point_mask,
    float* out, float* dpts) {
    head_phase(blockIdx.x, threadIdx.x, g1, Yb2, b_last, w_fc, b_fc,
               base_point, point_mask, out, dpts);
}

__global__ __launch_bounds__(256, 2) void lap_wrap(const bf16* adjB, const float* dpts,
                                                   float* outlap) {
    __shared__ char lds[32768];
    lap_phase(lds, blockIdx.x, threadIdx.x, adjB, dpts, outlap);
}

extern "C" void kernel_launch(void* const* d_in, const int* in_sizes, int n_in,
                              void* d_out, int out_size, void* d_ws, size_t ws_size,
                              hipStream_t stream) {
    const float* features   = (const float*)d_in[0];
    const float* base_point = (const float*)d_in[1];
    const float* adj        = (const float*)d_in[2];
    const float* point_mask = (const float*)d_in[3];
    const float* w_first    = (const float*)d_in[4];
    const float* b_first    = (const float*)d_in[5];
    const float* w_mid      = (const float*)d_in[6];
    const float* b_mid      = (const float*)d_in[7];
    const float* w_last     = (const float*)d_in[8];
    const float* b_last     = (const float*)d_in[9];
    const float* w_fc       = (const float*)d_in[10];
    const float* b_fc       = (const float*)d_in[11];
    float* out = (float*)d_out;
    char* W = (char*)d_ws;

    void* args[] = {
        (void*)&adj, (void*)&features, (void*)&base_point, (void*)&point_mask,
        (void*)&w_first, (void*)&b_first, (void*)&w_mid, (void*)&b_mid,
        (void*)&w_last, (void*)&b_last, (void*)&w_fc, (void*)&b_fc,
        (void*)&out, (void*)&W
    };
    hipError_t err = hipLaunchCooperativeKernel((void*)fused_kernel, dim3(512), dim3(256),
                                                args, 0, stream);
    if (err != hipSuccess) {
        // deterministic fallback: same phases as discrete dispatches
        bf16* adjB = (bf16*)W;
        bf16* wT   = (bf16*)(W + 16777216);
        bf16* x0p  = (bf16*)(W + 20447232);
        bf16* g1b1 = (bf16*)(W + 24641536);
        bf16* g2T  = (bf16*)(W + 26738688);
        bf16* Yb   = (bf16*)(W + 28835840);
        float* dpts = (float*)(W + 51904512);

        prep_wrap<<<512, 256, 0, stream>>>(adj, adjB, features, base_point, x0p,
                                           w_first, w_mid, w_last, wT);
        for (int k = 0; k < 14; ++k) {
            LayerPtrs L = layer_ptrs(k, W, b_first, b_mid);
            s_wrap<<<512, 256, 0, stream>>>(L.gprev, L.Ybp, L.bb1, L.bb2, L.resp, L.rl,
                                            wT + (size_t)2 * k * 65536, L.xw, L.g1o, g2T);
            b_wrap<<<512, 256, 0, stream>>>(adjB, g2T, Yb);
        }
        head_wrap<<<512, 256, 0, stream>>>(g1b1, Yb, b_last, w_fc, b_fc,
                                           base_point, point_mask, out, dpts);
        lap_wrap<<<512, 256, 0, stream>>>(adjB, dpts, out + 4 * BB * NN);
    }
}

// Round 11
// 316.983 us; speedup vs baseline: 6.5957x; 6.5957x over previous
//
#include <hip/hip_runtime.h>
#include <hip/hip_bf16.h>
#include <math.h>

#define BB 2
#define NN 2048
#define HH 256
#define WW 256
#define CC 128
#define MIDN 6
#define YSTR 1048576   // elements per Y partial ([4096][256])

typedef __hip_bfloat16 bf16;
typedef short short8 __attribute__((ext_vector_type(8)));
typedef float f32x4 __attribute__((ext_vector_type(4)));
typedef unsigned short ushort4v __attribute__((ext_vector_type(4)));

__device__ inline float bf2f(unsigned short u) {
    return __uint_as_float(((unsigned int)u) << 16);
}
__device__ inline unsigned short f2bf_bits(float f) {
    __hip_bfloat16 h = __float2bfloat16(f);
    return *reinterpret_cast<unsigned short*>(&h);
}

// ======== conv: adj f32 -> bf16, pure streaming. 2048 blocks x 256 thr, 16 f32/thread ========
__global__ __launch_bounds__(256) void conv_kernel(const float* __restrict__ adj,
                                                   bf16* __restrict__ adjB) {
    size_t base = ((size_t)blockIdx.x * 256 + threadIdx.x) * 16;
    #pragma unroll
    for (int h = 0; h < 2; ++h) {
        float4 f0 = *(const float4*)(adj + base + h * 8);
        float4 f1 = *(const float4*)(adj + base + h * 8 + 4);
        short8 v;
        v[0] = (short)f2bf_bits(f0.x); v[1] = (short)f2bf_bits(f0.y);
        v[2] = (short)f2bf_bits(f0.z); v[3] = (short)f2bf_bits(f0.w);
        v[4] = (short)f2bf_bits(f1.x); v[5] = (short)f2bf_bits(f1.y);
        v[6] = (short)f2bf_bits(f1.z); v[7] = (short)f2bf_bits(f1.w);
        *(short8*)(adjB + base + h * 8) = v;
    }
}

// ======== misc: interp (0..1023) | weight transpose (1024..2815) ========
__global__ void misc_kernel(const float* __restrict__ features, const float* __restrict__ base_point,
                            bf16* __restrict__ x0p,
                            const float* __restrict__ w_first, const float* __restrict__ w_mid,
                            const float* __restrict__ w_last, bf16* __restrict__ wT) {
    __shared__ float tbuf[32][33];
    int bid = blockIdx.x;
    int t = threadIdx.x;
    if (bid < 1024) {
        // one wave per point, 2 channels per lane
        int wv = t >> 6, lane = t & 63;
        int idx = bid * 4 + wv;             // 0..4095
        int b   = idx >> 11;
        float bx = base_point[idx * 2 + 0];
        float by = base_point[idx * 2 + 1];
        float xs = bx * (float)WW;
        float ys = by * (float)HH;
        float x0f = floorf(xs), y0f = floorf(ys);
        float x1f = x0f + 1.f, y1f = y0f + 1.f;
        float w00 = (x1f - xs) * (y1f - ys);
        float w01 = (x1f - xs) * (ys - y0f);
        float w10 = (xs - x0f) * (y1f - ys);
        float w11 = (xs - x0f) * (ys - y0f);
        int X0 = (int)fminf(fmaxf(x0f, 0.f), (float)(WW - 1));
        int X1 = (int)fminf(fmaxf(x1f, 0.f), (float)(WW - 1));
        int Y0 = (int)fminf(fmaxf(y0f, 0.f), (float)(HH - 1));
        int Y1 = (int)fminf(fmaxf(y1f, 0.f), (float)(HH - 1));
        int p00 = Y0 * WW + X0, p01 = Y1 * WW + X0;
        int p10 = Y0 * WW + X1, p11 = Y1 * WW + X1;
        int c0 = lane * 2;
        const float* f0 = features + (size_t)(b * CC + c0) * (HH * WW);
        const float* f1 = f0 + HH * WW;
        float v0 = w00 * f0[p00] + w01 * f0[p01] + w10 * f0[p10] + w11 * f0[p11];
        float v1 = w00 * f1[p00] + w01 * f1[p01] + w10 * f1[p10] + w11 * f1[p11];
        unsigned int pk = (unsigned int)f2bf_bits(v0) | ((unsigned int)f2bf_bits(v1) << 16);
        *(unsigned int*)(x0p + (size_t)idx * 256 + c0) = pk;
        unsigned int pk2 = 0;
        if (lane == 0)
            pk2 = (unsigned int)f2bf_bits(bx) | ((unsigned int)f2bf_bits(by) << 16);
        *(unsigned int*)(x0p + (size_t)idx * 256 + 128 + c0) = pk2;
    } else {
        int idx = bid - 1024;               // 0..1791
        int m   = idx >> 6;                 // matrix 0..27
        int sub = idx & 63;
        int bx = sub & 7, by = sub >> 3;
        const float* S; int R;
        if (m < 2)       { S = w_first + (size_t)m * 130 * 256; R = 130; }
        else if (m < 26) { S = w_mid + (size_t)(m - 2) * 65536; R = 256; }
        else             { S = w_last + (size_t)(m - 26) * 65536; R = 256; }
        bf16* D = wT + (size_t)m * 65536;
        int tx = t & 31, ty = t >> 5;
        int c0 = bx * 32, r0 = by * 32;
        #pragma unroll
        for (int k = 0; k < 4; ++k) {
            int r = r0 + ty + 8 * k;
            tbuf[ty + 8 * k][tx] = (r < R) ? S[(size_t)r * 256 + c0 + tx] : 0.f;
        }
        __syncthreads();
        #pragma unroll
        for (int k = 0; k < 4; ++k) {
            int c = c0 + ty + 8 * k;
            D[(size_t)c * 256 + r0 + tx] = __float2bfloat16(tbuf[tx][ty + 8 * k]);
        }
    }
}

// ======== S: x = combine(gprev + Y0..Y3 + b1 + b2 [+res][relu]) ; [g1|g2T] = x @ wcat ========
// single-phase: stage ALL weights (64 KB, 4 K-planes) + full A tile (16 KB), 1 barrier, 32 MFMA.
// 512 blocks 1-D (XCD-swizzled): lin = ct(4) + 4*rt(128). 256 threads.
__global__ __launch_bounds__(256, 2) void s_kernel(const bf16* __restrict__ gprev,
                                                   const bf16* __restrict__ Yb,
                                                   const float* __restrict__ bias1,
                                                   const float* __restrict__ bias2,
                                                   const bf16* __restrict__ res,
                                                   int relu,
                                                   const bf16* __restrict__ wcat,
                                                   bf16* __restrict__ xR,
                                                   bf16* __restrict__ g1out,
                                                   bf16* __restrict__ g2T) {
    __shared__ char lds[81920];         // Bl: 4 planes x 16 KB @0 ; Al: 4 planes x 4 KB @65536
    char* Bl = lds;
    char* Al = lds + 65536;
    int tid = threadIdx.x;
    int bid = blockIdx.x;
    int lin = (bid & 7) * 64 + (bid >> 3);
    int ct = lin & 3, rt = lin >> 2;
    int lane = tid & 63, w = tid >> 6;
    int wr = w >> 1, wc = w & 1;       // wave: 16 rows x 64 outfeats
    int row16 = lane & 15, kg = lane >> 4;

    // ---- stage all weights: plane p holds K-chunk p (64 wide), rows 0..127, 128B rows swizzled ----
    #pragma unroll
    for (int rnd = 0; rnd < 16; ++rnd) {
        int plane = rnd >> 2;
        int dp = (rnd & 3) * 4096 + tid * 16;   // within-plane byte
        int row = dp >> 7;                       // 0..127
        int cb = dp & 127;
        int sc = (cb ^ ((row & 7) << 4)) >> 1;
        __builtin_amdgcn_global_load_lds(
            (const __attribute__((address_space(1))) void*)(wcat + (size_t)(ct * 128 + row) * 256 + plane * 64 + sc),
            (__attribute__((address_space(3))) void*)(Bl + plane * 16384 + (rnd & 3) * 4096 + (w << 10)),
            16, 0, 0);
    }

    // ---- A combine: 4 planes, per thread one short8 per plane ----
    {
        int arow = tid >> 3;                 // 0..31
        int acb  = (tid * 16) & 127;
        int ridx = rt * 32 + arow;
        int awb  = arow * 128 + (acb ^ ((arow & 7) << 4));
        #pragma unroll
        for (int rnd = 0; rnd < 4; ++rnd) {
            int gcol = rnd * 64 + (acb >> 1);
            size_t off = (size_t)ridx * 256 + gcol;
            short8 pk;
            if (Yb) {
                short8 gv  = *(const short8*)(gprev + off);
                float fv[8];
                #pragma unroll
                for (int j = 0; j < 8; ++j) fv[j] = bf2f((unsigned short)gv[j]);
                #pragma unroll
                for (int p = 0; p < 4; ++p) {
                    short8 yv = *(const short8*)(Yb + (size_t)p * YSTR + off);
                    #pragma unroll
                    for (int j = 0; j < 8; ++j) fv[j] += bf2f((unsigned short)yv[j]);
                }
                short8 rv = {};
                if (res) rv = *(const short8*)(res + off);
                #pragma unroll
                for (int j = 0; j < 8; ++j) {
                    float f = fv[j] + bias1[gcol + j] + bias2[gcol + j];
                    if (res)  f += bf2f((unsigned short)rv[j]);
                    if (relu) f = fmaxf(f, 0.f);
                    pk[j] = (short)f2bf_bits(f);
                }
            } else {
                pk = *(const short8*)(gprev + off);
            }
            if (ct == 0) *(short8*)(xR + off) = pk;
            *(short8*)(Al + rnd * 4096 + awb) = pk;
        }
    }

    asm volatile("s_waitcnt vmcnt(0) lgkmcnt(0)" ::: "memory");
    __builtin_amdgcn_s_barrier();

    f32x4 acc[4] = {};
    int arow = wr * 16 + row16;
    #pragma unroll
    for (int kk = 0; kk < 8; ++kk) {
        int plane = kk >> 1, kk2 = kk & 1;
        int kof = kk2 * 64 + kg * 16;
        short8 a = *(const short8*)(Al + plane * 4096 + arow * 128 + (kof ^ ((arow & 7) << 4)));
        #pragma unroll
        for (int nf = 0; nf < 4; ++nf) {
            int fr = wc * 64 + nf * 16 + row16;
            short8 bfr = *(const short8*)(Bl + plane * 16384 + fr * 128 + (kof ^ ((fr & 7) << 4)));
            acc[nf] = __builtin_amdgcn_mfma_f32_16x16x32_bf16(a, bfr, acc[nf], 0, 0, 0);
        }
    }

    int cbase = ct * 128 + wc * 64;
    int rb = rt * 32 + wr * 16 + kg * 4;
    if (cbase < 256) {
        #pragma unroll
        for (int nf = 0; nf < 4; ++nf) {
            int c = cbase + nf * 16 + row16;
            #pragma unroll
            for (int j = 0; j < 4; ++j)
                *reinterpret_cast<unsigned short*>(&g1out[(size_t)(rb + j) * 256 + c]) = f2bf_bits(acc[nf][j]);
        }
    } else {
        #pragma unroll
        for (int nf = 0; nf < 4; ++nf) {
            int c = cbase - 256 + nf * 16 + row16;
            ushort4v pk;
            #pragma unroll
            for (int j = 0; j < 4; ++j) pk[j] = f2bf_bits(acc[nf][j]);
            *(ushort4v*)(g2T + (size_t)c * 4096 + rb) = pk;
        }
    }
}

// ======== B: Y[ks] = adj[:, ks quarter] @ g2 — BM=128, BN=64, split-K=4 ========
// 3-buffer 2-ahead counted-vmcnt(12) pipeline (3 x 24 KB LDS -> 2 blocks/CU).
// 512 blocks 1-D (XCD-swizzled): lin = (bid&7)*64 + bid>>3; ct=lin&3, rt=(lin>>2)&15, z=lin>>6 (b=z>>2, ks=z&3).
__global__ __launch_bounds__(256, 2) void adjb_kernel(const bf16* __restrict__ adjB,
                                                      const bf16* __restrict__ g2T,
                                                      bf16* __restrict__ Ybase) {
    __shared__ char lds[73728];         // buf i @ i*24576: A 16 KB, B 8 KB @ +16384
    int tid = threadIdx.x;
    int bid = blockIdx.x;
    int lin = (bid & 7) * 64 + (bid >> 3);
    int ct = lin & 3, rt = (lin >> 2) & 15, z = lin >> 6;
    int b = z >> 2, ks = z & 3;
    const bf16* Aadj = adjB + (size_t)b * NN * NN + (size_t)(rt * 128) * NN + ks * 512;
    const bf16* Bg   = g2T + (size_t)(ct * 64) * 4096 + b * NN + ks * 512;
    bf16* Yo = Ybase + (size_t)ks * YSTR;
    int lane = tid & 63, w = tid >> 6;
    int wr = w >> 1, wc = w & 1;       // wave tile: 64 rows x 32 cols
    int row16 = lane & 15, kg = lane >> 4;
    f32x4 acc[4][2] = {};

    #define STAGE(BUF, IT)                                                                \
        {                                                                                 \
            int k0 = (IT) * 64;                                                           \
            _Pragma("unroll")                                                             \
            for (int rnd = 0; rnd < 4; ++rnd) {                                           \
                int d = tid * 16 + rnd * 4096;                                            \
                int row = d >> 7, cb = d & 127;                                           \
                int sc = (cb ^ ((row & 7) << 4)) >> 1;                                    \
                __builtin_amdgcn_global_load_lds(                                         \
                    (const __attribute__((address_space(1))) void*)(Aadj + (size_t)row * NN + k0 + sc), \
                    (__attribute__((address_space(3))) void*)(lds + (BUF) * 24576 + rnd * 4096 + (w << 10)), \
                    16, 0, 0);                                                            \
            }                                                                             \
            _Pragma("unroll")                                                             \
            for (int rnd = 0; rnd < 2; ++rnd) {                                           \
                int d = tid * 16 + rnd * 4096;                                            \
                int row = d >> 7, cb = d & 127;                                           \
                int sc = (cb ^ ((row & 7) << 4)) >> 1;                                    \
                __builtin_amdgcn_global_load_lds(                                         \
                    (const __attribute__((address_space(1))) void*)(Bg + (size_t)row * 4096 + k0 + sc), \
                    (__attribute__((address_space(3))) void*)(lds + (BUF) * 24576 + 16384 + rnd * 4096 + (w << 10)), \
                    16, 0, 0);                                                            \
            }                                                                             \
        }

    #define MFMA_STEP(BUF)                                                                \
        _Pragma("unroll")                                                                 \
        for (int kk = 0; kk < 2; ++kk) {                                                  \
            short8 a[4], bfr[2];                                                          \
            _Pragma("unroll")                                                             \
            for (int mf = 0; mf < 4; ++mf) {                                              \
                int row = wr * 64 + mf * 16 + row16;                                      \
                a[mf] = *(const short8*)(lds + (BUF) * 24576 + row * 128 +                \
                          (((kk * 64) + kg * 16) ^ ((row & 7) << 4)));                    \
            }                                                                             \
            _Pragma("unroll")                                                             \
            for (int nf = 0; nf < 2; ++nf) {                                              \
                int fr = wc * 32 + nf * 16 + row16;                                       \
                bfr[nf] = *(const short8*)(lds + (BUF) * 24576 + 16384 + fr * 128 +       \
                          (((kk * 64) + kg * 16) ^ ((fr & 7) << 4)));                     \
            }                                                                             \
            _Pragma("unroll")                                                             \
            for (int mf = 0; mf < 4; ++mf)                                                \
                _Pragma("unroll")                                                         \
                for (int nf = 0; nf < 2; ++nf)                                            \
                    acc[mf][nf] = __builtin_amdgcn_mfma_f32_16x16x32_bf16(a[mf], bfr[nf], acc[mf][nf], 0, 0, 0); \
        }

    // 2-ahead schedule: stage(i+2) BEFORE MFMA(i); wait vmcnt(12) leaves iters i+1,i+2 in flight.
    #define ITER_DEEP(CURBUF, NXTBUF, NXTIT)                                              \
        STAGE(NXTBUF, NXTIT);                                                             \
        asm volatile("s_waitcnt vmcnt(12)" ::: "memory");                                 \
        __builtin_amdgcn_s_barrier();                                                     \
        MFMA_STEP(CURBUF);                                                                \
        __builtin_amdgcn_s_barrier();

    STAGE(0, 0);
    STAGE(1, 1);
    ITER_DEEP(0, 2, 2)      // it 0, stage it2
    ITER_DEEP(1, 0, 3)      // it 1, stage it3
    ITER_DEEP(2, 1, 4)      // it 2, stage it4
    ITER_DEEP(0, 2, 5)      // it 3, stage it5
    ITER_DEEP(1, 0, 6)      // it 4, stage it6
    ITER_DEEP(2, 1, 7)      // it 5, stage it7
    // it 6 (no stage)
    asm volatile("s_waitcnt vmcnt(6)" ::: "memory");
    __builtin_amdgcn_s_barrier();
    MFMA_STEP(0);
    __builtin_amdgcn_s_barrier();
    // it 7
    asm volatile("s_waitcnt vmcnt(0)" ::: "memory");
    __builtin_amdgcn_s_barrier();
    MFMA_STEP(1);

    #pragma unroll
    for (int mf = 0; mf < 4; ++mf) {
        #pragma unroll
        for (int nf = 0; nf < 2; ++nf) {
            int c  = ct * 64 + wc * 32 + nf * 16 + row16;
            int r0 = b * NN + rt * 128 + wr * 64 + mf * 16 + kg * 4;
            #pragma unroll
            for (int j = 0; j < 4; ++j)
                *reinterpret_cast<unsigned short*>(&Yo[(size_t)(r0 + j) * 256 + c]) = f2bf_bits(acc[mf][nf][j]);
        }
    }
    #undef STAGE
    #undef MFMA_STEP
    #undef ITER_DEEP
}

// ======== head: z = g1 + ΣY + b_last ; gcn_pred = z@w_fc + b_fc ; outputs; zero lap accumulators ========
// 64 blocks x 256 threads: 4 threads per row, 64 dims each, quad shfl-reduce.
__global__ void head_kernel(const bf16* __restrict__ g1, const bf16* __restrict__ Yb,
                            const float* __restrict__ b_last,
                            const float* __restrict__ w_fc, const float* __restrict__ b_fc,
                            const float* __restrict__ base_point, const float* __restrict__ point_mask,
                            float* __restrict__ out, float* __restrict__ dpts) {
    if (blockIdx.x == 0 && threadIdx.x < 2)
        out[4 * BB * NN + threadIdx.x] = 0.f;
    int t = threadIdx.x;
    int row = blockIdx.x * 64 + (t >> 2);
    int q = t & 3;
    float s0 = 0.f, s1 = 0.f;
    #pragma unroll
    for (int d8 = 0; d8 < 64; d8 += 8) {
        int d = q * 64 + d8;
        size_t off = (size_t)row * 256 + d;
        short8 a = *(const short8*)(g1 + off);
        float zv[8];
        #pragma unroll
        for (int j = 0; j < 8; ++j) zv[j] = bf2f((unsigned short)a[j]);
        #pragma unroll
        for (int p = 0; p < 4; ++p) {
            short8 yv = *(const short8*)(Yb + (size_t)p * YSTR + off);
            #pragma unroll
            for (int j = 0; j < 8; ++j) zv[j] += bf2f((unsigned short)yv[j]);
        }
        #pragma unroll
        for (int j = 0; j < 8; ++j) {
            float z = zv[j] + b_last[d + j] + b_last[256 + d + j];
            s0 += z * w_fc[(d + j) * 2 + 0];
            s1 += z * w_fc[(d + j) * 2 + 1];
        }
    }
    s0 += __shfl_xor(s0, 1); s0 += __shfl_xor(s0, 2);
    s1 += __shfl_xor(s1, 1); s1 += __shfl_xor(s1, 2);
    if (q == 0) {
        s0 += b_fc[0];
        s1 += b_fc[1];
        float m  = point_mask[row];
        float p0 = base_point[row * 2 + 0] + s0 * m;
        float p1 = base_point[row * 2 + 1] + s1 * m;
        out[row * 2 + 0] = p0;
        out[row * 2 + 1] = p1;
        out[2 * BB * NN + row * 2 + 0] = s0;
        out[2 * BB * NN + row * 2 + 1] = s1;
        dpts[row * 2 + 0] = s0 * m;
        dpts[row * 2 + 1] = s1 * m;
    }
}

// ======== lap: t = sqrt(|d - adj@d|^2 + 1e-10) per row; block-reduce; atomicAdd mean ========
__global__ void lap_rows(const bf16* __restrict__ adjB, const float* __restrict__ dpts,
                         float* __restrict__ outlap) {
    __shared__ float sd[4];
    int w    = threadIdx.x >> 6;
    int lane = threadIdx.x & 63;
    int row  = blockIdx.x * 4 + w;
    int b = row >> 11, n = row & 2047;
    const bf16* ar = adjB + (size_t)b * NN * NN + (size_t)n * NN;
    const float* db = dpts + (size_t)b * NN * 2;
    float s0 = 0.f, s1 = 0.f;
    for (int k4 = 0; k4 < 4; ++k4) {
        int k = k4 * 512 + lane * 8;
        short8 av = *(const short8*)(ar + k);
        #pragma unroll
        for (int j = 0; j < 8; ++j) {
            float a = bf2f((unsigned short)av[j]);
            float2 dv = *(const float2*)(db + (k + j) * 2);
            s0 += a * dv.x;
            s1 += a * dv.y;
        }
    }
    for (int off = 32; off; off >>= 1) {
        s0 += __shfl_xor(s0, off);
        s1 += __shfl_xor(s1, off);
    }
    if (lane == 0) {
        float e0 = dpts[(size_t)row * 2 + 0] - s0;
        float e1 = dpts[(size_t)row * 2 + 1] - s1;
        sd[w] = sqrtf(e0 * e0 + e1 * e1 + 1e-10f);
    }
    __syncthreads();
    if (threadIdx.x == 0) {
        float s = (sd[0] + sd[1] + sd[2] + sd[3]) * (1.f / (float)NN);
        atomicAdd(&outlap[b], s);
    }
}

extern "C" void kernel_launch(void* const* d_in, const int* in_sizes, int n_in,
                              void* d_out, int out_size, void* d_ws, size_t ws_size,
                              hipStream_t stream) {
    const float* features   = (const float*)d_in[0];
    const float* base_point = (const float*)d_in[1];
    const float* adj        = (const float*)d_in[2];
    const float* point_mask = (const float*)d_in[3];
    const float* w_first    = (const float*)d_in[4];
    const float* b_first    = (const float*)d_in[5];
    const float* w_mid      = (const float*)d_in[6];
    const float* b_mid      = (const float*)d_in[7];
    const float* w_last     = (const float*)d_in[8];
    const float* b_last     = (const float*)d_in[9];
    const float* w_fc       = (const float*)d_in[10];
    const float* b_fc       = (const float*)d_in[11];
    float* out = (float*)d_out;
    char* W = (char*)d_ws;

    bf16* adjB   = (bf16*)W;                          // 16.78 MB
    bf16* wT     = (bf16*)(W + 16777216);             // 3.67 MB
    bf16* x0p    = (bf16*)(W + 20447232);
    bf16* g1b[2] = { (bf16*)(W + 22544384), (bf16*)(W + 24641536) };
    bf16* g2T    = (bf16*)(W + 26738688);
    bf16* Yb     = (bf16*)(W + 28835840);             // 4 partials x 2 MB
    bf16* xsl[2] = { (bf16*)(W + 45613056), (bf16*)(W + 47710208) };
    bf16* xscr   = (bf16*)(W + 49807360);
    float* dpts  = (float*)(W + 51904512);

    conv_kernel<<<2048, 256, 0, stream>>>(adj, adjB);
    misc_kernel<<<2816, 256, 0, stream>>>(features, base_point, x0p,
                                          w_first, w_mid, w_last, wT);

    // L0
    s_kernel<<<512, 256, 0, stream>>>(x0p, nullptr, nullptr, nullptr, nullptr, 0,
                                      wT, xscr, g1b[0], g2T);
    adjb_kernel<<<512, 256, 0, stream>>>(adjB, g2T, Yb);

    for (int k = 1; k < 14; ++k) {
        const float *bb1, *bb2;
        const bf16* resp = nullptr;
        bf16* xw;
        int rl;
        if (k == 1) {
            bb1 = b_first; bb2 = b_first + 256; rl = 0; xw = xsl[0];
        } else if ((k & 1) == 0) {
            int m = (k - 2) / 2;
            bb1 = b_mid + (size_t)m * 1024; bb2 = bb1 + 256;
            rl = 1; xw = xscr;
        } else {
            int m = (k - 3) / 2;
            bb1 = b_mid + (size_t)m * 1024 + 512; bb2 = bb1 + 256;
            rl = 1;
            resp = xsl[m & 1];
            xw   = xsl[((k - 1) / 2) & 1];
        }
        s_kernel<<<512, 256, 0, stream>>>(g1b[(k - 1) & 1], Yb, bb1, bb2, resp, rl,
                                          wT + (size_t)2 * k * 65536, xw, g1b[k & 1], g2T);
        adjb_kernel<<<512, 256, 0, stream>>>(adjB, g2T, Yb);
    }

    head_kernel<<<64, 256, 0, stream>>>(g1b[1], Yb, b_last, w_fc, b_fc,
                                        base_point, point_mask, out, dpts);
    lap_rows<<<1024, 256, 0, stream>>>(adjB, dpts, out + 4 * BB * NN);
}

// Round 12
// 311.726 us; speedup vs baseline: 6.7070x; 1.0169x over previous
//
#include <hip/hip_runtime.h>
#include <hip/hip_bf16.h>
#include <math.h>

#define BB 2
#define NN 2048
#define HH 256
#define WW 256
#define CC 128
#define MIDN 6
#define YSTR 1048576   // elements per Y partial ([4096][256])

typedef __hip_bfloat16 bf16;
typedef short short8 __attribute__((ext_vector_type(8)));
typedef short short4v __attribute__((ext_vector_type(4)));
typedef float f32x4 __attribute__((ext_vector_type(4)));
typedef unsigned short ushort4v __attribute__((ext_vector_type(4)));

__device__ inline float bf2f(unsigned short u) {
    return __uint_as_float(((unsigned int)u) << 16);
}
__device__ inline unsigned short f2bf_bits(float f) {
    __hip_bfloat16 h = __float2bfloat16(f);
    return *reinterpret_cast<unsigned short*>(&h);
}

// ======== conv: adj f32 -> bf16, lane-contiguous float4 reads / 8B writes. ========
// 2048 blocks x 256 thr x 4 iters: each iter, wave reads 64 contiguous float4 (1 KB sweep).
__global__ __launch_bounds__(256) void conv_kernel(const float* __restrict__ adj,
                                                   bf16* __restrict__ adjB) {
    size_t blockBase = (size_t)blockIdx.x * 4096;     // 4096 floats per block
    #pragma unroll
    for (int it = 0; it < 4; ++it) {
        size_t i = blockBase + (size_t)it * 1024 + threadIdx.x * 4;
        float4 f = *(const float4*)(adj + i);
        short4v v;
        v[0] = (short)f2bf_bits(f.x); v[1] = (short)f2bf_bits(f.y);
        v[2] = (short)f2bf_bits(f.z); v[3] = (short)f2bf_bits(f.w);
        *(short4v*)(adjB + i) = v;
    }
}

// ======== misc: interp (0..1023) | weight transpose (1024..2815) ========
__global__ void misc_kernel(const float* __restrict__ features, const float* __restrict__ base_point,
                            bf16* __restrict__ x0p,
                            const float* __restrict__ w_first, const float* __restrict__ w_mid,
                            const float* __restrict__ w_last, bf16* __restrict__ wT) {
    __shared__ float tbuf[32][33];
    int bid = blockIdx.x;
    int t = threadIdx.x;
    if (bid < 1024) {
        // one wave per point, 2 channels per lane
        int wv = t >> 6, lane = t & 63;
        int idx = bid * 4 + wv;             // 0..4095
        int b   = idx >> 11;
        float bx = base_point[idx * 2 + 0];
        float by = base_point[idx * 2 + 1];
        float xs = bx * (float)WW;
        float ys = by * (float)HH;
        float x0f = floorf(xs), y0f = floorf(ys);
        float x1f = x0f + 1.f, y1f = y0f + 1.f;
        float w00 = (x1f - xs) * (y1f - ys);
        float w01 = (x1f - xs) * (ys - y0f);
        float w10 = (xs - x0f) * (y1f - ys);
        float w11 = (xs - x0f) * (ys - y0f);
        int X0 = (int)fminf(fmaxf(x0f, 0.f), (float)(WW - 1));
        int X1 = (int)fminf(fmaxf(x1f, 0.f), (float)(WW - 1));
        int Y0 = (int)fminf(fmaxf(y0f, 0.f), (float)(HH - 1));
        int Y1 = (int)fminf(fmaxf(y1f, 0.f), (float)(HH - 1));
        int p00 = Y0 * WW + X0, p01 = Y1 * WW + X0;
        int p10 = Y0 * WW + X1, p11 = Y1 * WW + X1;
        int c0 = lane * 2;
        const float* f0 = features + (size_t)(b * CC + c0) * (HH * WW);
        const float* f1 = f0 + HH * WW;
        float v0 = w00 * f0[p00] + w01 * f0[p01] + w10 * f0[p10] + w11 * f0[p11];
        float v1 = w00 * f1[p00] + w01 * f1[p01] + w10 * f1[p10] + w11 * f1[p11];
        unsigned int pk = (unsigned int)f2bf_bits(v0) | ((unsigned int)f2bf_bits(v1) << 16);
        *(unsigned int*)(x0p + (size_t)idx * 256 + c0) = pk;
        unsigned int pk2 = 0;
        if (lane == 0)
            pk2 = (unsigned int)f2bf_bits(bx) | ((unsigned int)f2bf_bits(by) << 16);
        *(unsigned int*)(x0p + (size_t)idx * 256 + 128 + c0) = pk2;
    } else {
        int idx = bid - 1024;               // 0..1791
        int m   = idx >> 6;                 // matrix 0..27
        int sub = idx & 63;
        int bx = sub & 7, by = sub >> 3;
        const float* S; int R;
        if (m < 2)       { S = w_first + (size_t)m * 130 * 256; R = 130; }
        else if (m < 26) { S = w_mid + (size_t)(m - 2) * 65536; R = 256; }
        else             { S = w_last + (size_t)(m - 26) * 65536; R = 256; }
        bf16* D = wT + (size_t)m * 65536;
        int tx = t & 31, ty = t >> 5;
        int c0 = bx * 32, r0 = by * 32;
        #pragma unroll
        for (int k = 0; k < 4; ++k) {
            int r = r0 + ty + 8 * k;
            tbuf[ty + 8 * k][tx] = (r < R) ? S[(size_t)r * 256 + c0 + tx] : 0.f;
        }
        __syncthreads();
        #pragma unroll
        for (int k = 0; k < 4; ++k) {
            int c = c0 + ty + 8 * k;
            D[(size_t)c * 256 + r0 + tx] = __float2bfloat16(tbuf[tx][ty + 8 * k]);
        }
    }
}

// ======== S: x = combine(gprev + Y0..Y3 + b1 + b2 [+res][relu]) ; [g1|g2T] = x @ wcat ========
// single-phase: stage ALL weights (64 KB, 4 K-planes) + full A tile (16 KB), 1 barrier, 32 MFMA.
// 512 blocks 1-D (XCD-swizzled): lin = ct(4) + 4*rt(128). 256 threads.
__global__ __launch_bounds__(256, 2) void s_kernel(const bf16* __restrict__ gprev,
                                                   const bf16* __restrict__ Yb,
                                                   const float* __restrict__ bias1,
                                                   const float* __restrict__ bias2,
                                                   const bf16* __restrict__ res,
                                                   int relu,
                                                   const bf16* __restrict__ wcat,
                                                   bf16* __restrict__ xR,
                                                   bf16* __restrict__ g1out,
                                                   bf16* __restrict__ g2T) {
    __shared__ char lds[81920];         // Bl: 4 planes x 16 KB @0 ; Al: 4 planes x 4 KB @65536
    char* Bl = lds;
    char* Al = lds + 65536;
    int tid = threadIdx.x;
    int bid = blockIdx.x;
    int lin = (bid & 7) * 64 + (bid >> 3);
    int ct = lin & 3, rt = lin >> 2;
    int lane = tid & 63, w = tid >> 6;
    int wr = w >> 1, wc = w & 1;       // wave: 16 rows x 64 outfeats
    int row16 = lane & 15, kg = lane >> 4;

    // ---- stage all weights: plane p holds K-chunk p (64 wide), rows 0..127, 128B rows swizzled ----
    #pragma unroll
    for (int rnd = 0; rnd < 16; ++rnd) {
        int plane = rnd >> 2;
        int dp = (rnd & 3) * 4096 + tid * 16;   // within-plane byte
        int row = dp >> 7;                       // 0..127
        int cb = dp & 127;
        int sc = (cb ^ ((row & 7) << 4)) >> 1;
        __builtin_amdgcn_global_load_lds(
            (const __attribute__((address_space(1))) void*)(wcat + (size_t)(ct * 128 + row) * 256 + plane * 64 + sc),
            (__attribute__((address_space(3))) void*)(Bl + plane * 16384 + (rnd & 3) * 4096 + (w << 10)),
            16, 0, 0);
    }

    // ---- A combine: 4 planes, per thread one short8 per plane ----
    {
        int arow = tid >> 3;                 // 0..31
        int acb  = (tid * 16) & 127;
        int ridx = rt * 32 + arow;
        int awb  = arow * 128 + (acb ^ ((arow & 7) << 4));
        #pragma unroll
        for (int rnd = 0; rnd < 4; ++rnd) {
            int gcol = rnd * 64 + (acb >> 1);
            size_t off = (size_t)ridx * 256 + gcol;
            short8 pk;
            if (Yb) {
                short8 gv  = *(const short8*)(gprev + off);
                float fv[8];
                #pragma unroll
                for (int j = 0; j < 8; ++j) fv[j] = bf2f((unsigned short)gv[j]);
                #pragma unroll
                for (int p = 0; p < 4; ++p) {
                    short8 yv = *(const short8*)(Yb + (size_t)p * YSTR + off);
                    #pragma unroll
                    for (int j = 0; j < 8; ++j) fv[j] += bf2f((unsigned short)yv[j]);
                }
                short8 rv = {};
                if (res) rv = *(const short8*)(res + off);
                #pragma unroll
                for (int j = 0; j < 8; ++j) {
                    float f = fv[j] + bias1[gcol + j] + bias2[gcol + j];
                    if (res)  f += bf2f((unsigned short)rv[j]);
                    if (relu) f = fmaxf(f, 0.f);
                    pk[j] = (short)f2bf_bits(f);
                }
            } else {
                pk = *(const short8*)(gprev + off);
            }
            if (ct == 0) *(short8*)(xR + off) = pk;
            *(short8*)(Al + rnd * 4096 + awb) = pk;
        }
    }

    asm volatile("s_waitcnt vmcnt(0) lgkmcnt(0)" ::: "memory");
    __builtin_amdgcn_s_barrier();

    f32x4 acc[4] = {};
    int arow = wr * 16 + row16;
    #pragma unroll
    for (int kk = 0; kk < 8; ++kk) {
        int plane = kk >> 1, kk2 = kk & 1;
        int kof = kk2 * 64 + kg * 16;
        short8 a = *(const short8*)(Al + plane * 4096 + arow * 128 + (kof ^ ((arow & 7) << 4)));
        #pragma unroll
        for (int nf = 0; nf < 4; ++nf) {
            int fr = wc * 64 + nf * 16 + row16;
            short8 bfr = *(const short8*)(Bl + plane * 16384 + fr * 128 + (kof ^ ((fr & 7) << 4)));
            acc[nf] = __builtin_amdgcn_mfma_f32_16x16x32_bf16(a, bfr, acc[nf], 0, 0, 0);
        }
    }

    int cbase = ct * 128 + wc * 64;
    int rb = rt * 32 + wr * 16 + kg * 4;
    if (cbase < 256) {
        #pragma unroll
        for (int nf = 0; nf < 4; ++nf) {
            int c = cbase + nf * 16 + row16;
            #pragma unroll
            for (int j = 0; j < 4; ++j)
                *reinterpret_cast<unsigned short*>(&g1out[(size_t)(rb + j) * 256 + c]) = f2bf_bits(acc[nf][j]);
        }
    } else {
        #pragma unroll
        for (int nf = 0; nf < 4; ++nf) {
            int c = cbase - 256 + nf * 16 + row16;
            ushort4v pk;
            #pragma unroll
            for (int j = 0; j < 4; ++j) pk[j] = f2bf_bits(acc[nf][j]);
            *(ushort4v*)(g2T + (size_t)c * 4096 + rb) = pk;
        }
    }
}

// ======== B: Y[ks] = adj[:, ks quarter] @ g2 — BM=128, BN=64, split-K=4 ========
// double-buffered counted-vmcnt(6) pipeline (2 x 24 KB LDS). [R8-measured-best variant]
// 512 blocks 1-D (XCD-swizzled): lin = (bid&7)*64 + bid>>3; ct=lin&3, rt=(lin>>2)&15, z=lin>>6 (b=z>>2, ks=z&3).
__global__ __launch_bounds__(256, 2) void adjb_kernel(const bf16* __restrict__ adjB,
                                                      const bf16* __restrict__ g2T,
                                                      bf16* __restrict__ Ybase) {
    __shared__ char lds[49152];         // buf i @ i*24576: A 16 KB, B 8 KB @ +16384
    int tid = threadIdx.x;
    int bid = blockIdx.x;
    int lin = (bid & 7) * 64 + (bid >> 3);
    int ct = lin & 3, rt = (lin >> 2) & 15, z = lin >> 6;
    int b = z >> 2, ks = z & 3;
    const bf16* Aadj = adjB + (size_t)b * NN * NN + (size_t)(rt * 128) * NN + ks * 512;
    const bf16* Bg   = g2T + (size_t)(ct * 64) * 4096 + b * NN + ks * 512;
    bf16* Yo = Ybase + (size_t)ks * YSTR;
    int lane = tid & 63, w = tid >> 6;
    int wr = w >> 1, wc = w & 1;       // wave tile: 64 rows x 32 cols
    int row16 = lane & 15, kg = lane >> 4;
    f32x4 acc[4][2] = {};

    #define STAGE(BUF, IT)                                                                \
        {                                                                                 \
            int k0 = (IT) * 64;                                                           \
            _Pragma("unroll")                                                             \
            for (int rnd = 0; rnd < 4; ++rnd) {                                           \
                int d = tid * 16 + rnd * 4096;                                            \
                int row = d >> 7, cb = d & 127;                                           \
                int sc = (cb ^ ((row & 7) << 4)) >> 1;                                    \
                __builtin_amdgcn_global_load_lds(                                         \
                    (const __attribute__((address_space(1))) void*)(Aadj + (size_t)row * NN + k0 + sc), \
                    (__attribute__((address_space(3))) void*)(lds + (BUF) * 24576 + rnd * 4096 + (w << 10)), \
                    16, 0, 0);                                                            \
            }                                                                             \
            _Pragma("unroll")                                                             \
            for (int rnd = 0; rnd < 2; ++rnd) {                                           \
                int d = tid * 16 + rnd * 4096;                                            \
                int row = d >> 7, cb = d & 127;                                           \
                int sc = (cb ^ ((row & 7) << 4)) >> 1;                                    \
                __builtin_amdgcn_global_load_lds(                                         \
                    (const __attribute__((address_space(1))) void*)(Bg + (size_t)row * 4096 + k0 + sc), \
                    (__attribute__((address_space(3))) void*)(lds + (BUF) * 24576 + 16384 + rnd * 4096 + (w << 10)), \
                    16, 0, 0);                                                            \
            }                                                                             \
        }

    #define MFMA_STEP(BUF)                                                                \
        _Pragma("unroll")                                                                 \
        for (int kk = 0; kk < 2; ++kk) {                                                  \
            short8 a[4], bfr[2];                                                          \
            _Pragma("unroll")                                                             \
            for (int mf = 0; mf < 4; ++mf) {                                              \
                int row = wr * 64 + mf * 16 + row16;                                      \
                a[mf] = *(const short8*)(lds + (BUF) * 24576 + row * 128 +                \
                          (((kk * 64) + kg * 16) ^ ((row & 7) << 4)));                    \
            }                                                                             \
            _Pragma("unroll")                                                             \
            for (int nf = 0; nf < 2; ++nf) {                                              \
                int fr = wc * 32 + nf * 16 + row16;                                       \
                bfr[nf] = *(const short8*)(lds + (BUF) * 24576 + 16384 + fr * 128 +       \
                          (((kk * 64) + kg * 16) ^ ((fr & 7) << 4)));                     \
            }                                                                             \
            _Pragma("unroll")                                                             \
            for (int mf = 0; mf < 4; ++mf)                                                \
                _Pragma("unroll")                                                         \
                for (int nf = 0; nf < 2; ++nf)                                            \
                    acc[mf][nf] = __builtin_amdgcn_mfma_f32_16x16x32_bf16(a[mf], bfr[nf], acc[mf][nf], 0, 0, 0); \
        }

    #define ITER_MID(CURBUF, NXTBUF, NXTIT)                                               \
        STAGE(NXTBUF, NXTIT);                                                             \
        asm volatile("s_waitcnt vmcnt(6)" ::: "memory");                                  \
        __builtin_amdgcn_s_barrier();                                                     \
        MFMA_STEP(CURBUF);                                                                \
        __builtin_amdgcn_s_barrier();

    STAGE(0, 0);
    ITER_MID(0, 1, 1)       // it 0
    ITER_MID(1, 0, 2)       // it 1
    ITER_MID(0, 1, 3)       // it 2
    ITER_MID(1, 0, 4)       // it 3
    ITER_MID(0, 1, 5)       // it 4
    ITER_MID(1, 0, 6)       // it 5
    ITER_MID(0, 1, 7)       // it 6
    // it 7 (no further stage)
    asm volatile("s_waitcnt vmcnt(0)" ::: "memory");
    __builtin_amdgcn_s_barrier();
    MFMA_STEP(1);

    #pragma unroll
    for (int mf = 0; mf < 4; ++mf) {
        #pragma unroll
        for (int nf = 0; nf < 2; ++nf) {
            int c  = ct * 64 + wc * 32 + nf * 16 + row16;
            int r0 = b * NN + rt * 128 + wr * 64 + mf * 16 + kg * 4;
            #pragma unroll
            for (int j = 0; j < 4; ++j)
                *reinterpret_cast<unsigned short*>(&Yo[(size_t)(r0 + j) * 256 + c]) = f2bf_bits(acc[mf][nf][j]);
        }
    }
    #undef STAGE
    #undef MFMA_STEP
    #undef ITER_MID
}

// ======== head: z = g1 + ΣY + b_last ; gcn_pred = z@w_fc + b_fc ; outputs; zero lap accumulators ========
// 64 blocks x 256 threads: 4 threads per row, 64 dims each, quad shfl-reduce.
__global__ void head_kernel(const bf16* __restrict__ g1, const bf16* __restrict__ Yb,
                            const float* __restrict__ b_last,
                            const float* __restrict__ w_fc, const float* __restrict__ b_fc,
                            const float* __restrict__ base_point, const float* __restrict__ point_mask,
                            float* __restrict__ out, float* __restrict__ dpts) {
    if (blockIdx.x == 0 && threadIdx.x < 2)
        out[4 * BB * NN + threadIdx.x] = 0.f;
    int t = threadIdx.x;
    int row = blockIdx.x * 64 + (t >> 2);
    int q = t & 3;
    float s0 = 0.f, s1 = 0.f;
    #pragma unroll
    for (int d8 = 0; d8 < 64; d8 += 8) {
        int d = q * 64 + d8;
        size_t off = (size_t)row * 256 + d;
        short8 a = *(const short8*)(g1 + off);
        float zv[8];
        #pragma unroll
        for (int j = 0; j < 8; ++j) zv[j] = bf2f((unsigned short)a[j]);
        #pragma unroll
        for (int p = 0; p < 4; ++p) {
            short8 yv = *(const short8*)(Yb + (size_t)p * YSTR + off);
            #pragma unroll
            for (int j = 0; j < 8; ++j) zv[j] += bf2f((unsigned short)yv[j]);
        }
        #pragma unroll
        for (int j = 0; j < 8; ++j) {
            float z = zv[j] + b_last[d + j] + b_last[256 + d + j];
            s0 += z * w_fc[(d + j) * 2 + 0];
            s1 += z * w_fc[(d + j) * 2 + 1];
        }
    }
    s0 += __shfl_xor(s0, 1); s0 += __shfl_xor(s0, 2);
    s1 += __shfl_xor(s1, 1); s1 += __shfl_xor(s1, 2);
    if (q == 0) {
        s0 += b_fc[0];
        s1 += b_fc[1];
        float m  = point_mask[row];
        float p0 = base_point[row * 2 + 0] + s0 * m;
        float p1 = base_point[row * 2 + 1] + s1 * m;
        out[row * 2 + 0] = p0;
        out[row * 2 + 1] = p1;
        out[2 * BB * NN + row * 2 + 0] = s0;
        out[2 * BB * NN + row * 2 + 1] = s1;
        dpts[row * 2 + 0] = s0 * m;
        dpts[row * 2 + 1] = s1 * m;
    }
}

// ======== lap: t = sqrt(|d - adj@d|^2 + 1e-10) per row; block-reduce; atomicAdd mean ========
__global__ void lap_rows(const bf16* __restrict__ adjB, const float* __restrict__ dpts,
                         float* __restrict__ outlap) {
    __shared__ float sd[4];
    int w    = threadIdx.x >> 6;
    int lane = threadIdx.x & 63;
    int row  = blockIdx.x * 4 + w;
    int b = row >> 11, n = row & 2047;
    const bf16* ar = adjB + (size_t)b * NN * NN + (size_t)n * NN;
    const float* db = dpts + (size_t)b * NN * 2;
    float s0 = 0.f, s1 = 0.f;
    for (int k4 = 0; k4 < 4; ++k4) {
        int k = k4 * 512 + lane * 8;
        short8 av = *(const short8*)(ar + k);
        #pragma unroll
        for (int j = 0; j < 8; ++j) {
            float a = bf2f((unsigned short)av[j]);
            float2 dv = *(const float2*)(db + (k + j) * 2);
            s0 += a * dv.x;
            s1 += a * dv.y;
        }
    }
    for (int off = 32; off; off >>= 1) {
        s0 += __shfl_xor(s0, off);
        s1 += __shfl_xor(s1, off);
    }
    if (lane == 0) {
        float e0 = dpts[(size_t)row * 2 + 0] - s0;
        float e1 = dpts[(size_t)row * 2 + 1] - s1;
        sd[w] = sqrtf(e0 * e0 + e1 * e1 + 1e-10f);
    }
    __syncthreads();
    if (threadIdx.x == 0) {
        float s = (sd[0] + sd[1] + sd[2] + sd[3]) * (1.f / (float)NN);
        atomicAdd(&outlap[b], s);
    }
}

extern "C" void kernel_launch(void* const* d_in, const int* in_sizes, int n_in,
                              void* d_out, int out_size, void* d_ws, size_t ws_size,
                              hipStream_t stream) {
    const float* features   = (const float*)d_in[0];
    const float* base_point = (const float*)d_in[1];
    const float* adj        = (const float*)d_in[2];
    const float* point_mask = (const float*)d_in[3];
    const float* w_first    = (const float*)d_in[4];
    const float* b_first    = (const float*)d_in[5];
    const float* w_mid      = (const float*)d_in[6];
    const float* b_mid      = (const float*)d_in[7];
    const float* w_last     = (const float*)d_in[8];
    const float* b_last     = (const float*)d_in[9];
    const float* w_fc       = (const float*)d_in[10];
    const float* b_fc       = (const float*)d_in[11];
    float* out = (float*)d_out;
    char* W = (char*)d_ws;

    bf16* adjB   = (bf16*)W;                          // 16.78 MB
    bf16* wT     = (bf16*)(W + 16777216);             // 3.67 MB
    bf16* x0p    = (bf16*)(W + 20447232);
    bf16* g1b[2] = { (bf16*)(W + 22544384), (bf16*)(W + 24641536) };
    bf16* g2T    = (bf16*)(W + 26738688);
    bf16* Yb     = (bf16*)(W + 28835840);             // 4 partials x 2 MB
    bf16* xsl[2] = { (bf16*)(W + 45613056), (bf16*)(W + 47710208) };
    bf16* xscr   = (bf16*)(W + 49807360);
    float* dpts  = (float*)(W + 51904512);

    conv_kernel<<<2048, 256, 0, stream>>>(adj, adjB);
    misc_kernel<<<2816, 256, 0, stream>>>(features, base_point, x0p,
                                          w_first, w_mid, w_last, wT);

    // L0
    s_kernel<<<512, 256, 0, stream>>>(x0p, nullptr, nullptr, nullptr, nullptr, 0,
                                      wT, xscr, g1b[0], g2T);
    adjb_kernel<<<512, 256, 0, stream>>>(adjB, g2T, Yb);

    for (int k = 1; k < 14; ++k) {
        const float *bb1, *bb2;
        const bf16* resp = nullptr;
        bf16* xw;
        int rl;
        if (k == 1) {
            bb1 = b_first; bb2 = b_first + 256; rl = 0; xw = xsl[0];
        } else if ((k & 1) == 0) {
            int m = (k - 2) / 2;
            bb1 = b_mid + (size_t)m * 1024; bb2 = bb1 + 256;
            rl = 1; xw = xscr;
        } else {
            int m = (k - 3) / 2;
            bb1 = b_mid + (size_t)m * 1024 + 512; bb2 = bb1 + 256;
            rl = 1;
            resp = xsl[m & 1];
            xw   = xsl[((k - 1) / 2) & 1];
        }
        s_kernel<<<512, 256, 0, stream>>>(g1b[(k - 1) & 1], Yb, bb1, bb2, resp, rl,
                                          wT + (size_t)2 * k * 65536, xw, g1b[k & 1], g2T);
        adjb_kernel<<<512, 256, 0, stream>>>(adjB, g2T, Yb);
    }

    head_kernel<<<64, 256, 0, stream>>>(g1b[1], Yb, b_last, w_fc, b_fc,
                                        base_point, point_mask, out, dpts);
    lap_rows<<<1024, 256, 0, stream>>>(adjB, dpts, out + 4 * BB * NN);
}

// Round 13
// 303.083 us; speedup vs baseline: 6.8982x; 1.0285x over previous
//
#include <hip/hip_runtime.h>
#include <hip/hip_bf16.h>
#include <math.h>

#define BB 2
#define NN 2048
#define HH 256
#define WW 256
#define CC 128
#define MIDN 6
#define YSTR 1048576   // elements per Y partial ([4096][256])

typedef __hip_bfloat16 bf16;
typedef short short8 __attribute__((ext_vector_type(8)));
typedef short short4v __attribute__((ext_vector_type(4)));
typedef float f32x4 __attribute__((ext_vector_type(4)));
typedef unsigned short ushort4v __attribute__((ext_vector_type(4)));

__device__ inline float bf2f(unsigned short u) {
    return __uint_as_float(((unsigned int)u) << 16);
}
__device__ inline unsigned short f2bf_bits(float f) {
    __hip_bfloat16 h = __float2bfloat16(f);
    return *reinterpret_cast<unsigned short*>(&h);
}

// ======== conv: adj f32 -> bf16, lane-contiguous float4 reads / 8B writes. ========
__global__ __launch_bounds__(256) void conv_kernel(const float* __restrict__ adj,
                                                   bf16* __restrict__ adjB) {
    size_t blockBase = (size_t)blockIdx.x * 4096;     // 4096 floats per block
    #pragma unroll
    for (int it = 0; it < 4; ++it) {
        size_t i = blockBase + (size_t)it * 1024 + threadIdx.x * 4;
        float4 f = *(const float4*)(adj + i);
        short4v v;
        v[0] = (short)f2bf_bits(f.x); v[1] = (short)f2bf_bits(f.y);
        v[2] = (short)f2bf_bits(f.z); v[3] = (short)f2bf_bits(f.w);
        *(short4v*)(adjB + i) = v;
    }
}

// ======== misc: interp (0..1023) | weight transpose (1024..2815) ========
__global__ void misc_kernel(const float* __restrict__ features, const float* __restrict__ base_point,
                            bf16* __restrict__ x0p,
                            const float* __restrict__ w_first, const float* __restrict__ w_mid,
                            const float* __restrict__ w_last, bf16* __restrict__ wT) {
    __shared__ float tbuf[32][33];
    int bid = blockIdx.x;
    int t = threadIdx.x;
    if (bid < 1024) {
        // one wave per point, 2 channels per lane
        int wv = t >> 6, lane = t & 63;
        int idx = bid * 4 + wv;             // 0..4095
        int b   = idx >> 11;
        float bx = base_point[idx * 2 + 0];
        float by = base_point[idx * 2 + 1];
        float xs = bx * (float)WW;
        float ys = by * (float)HH;
        float x0f = floorf(xs), y0f = floorf(ys);
        float x1f = x0f + 1.f, y1f = y0f + 1.f;
        float w00 = (x1f - xs) * (y1f - ys);
        float w01 = (x1f - xs) * (ys - y0f);
        float w10 = (xs - x0f) * (y1f - ys);
        float w11 = (xs - x0f) * (ys - y0f);
        int X0 = (int)fminf(fmaxf(x0f, 0.f), (float)(WW - 1));
        int X1 = (int)fminf(fmaxf(x1f, 0.f), (float)(WW - 1));
        int Y0 = (int)fminf(fmaxf(y0f, 0.f), (float)(HH - 1));
        int Y1 = (int)fminf(fmaxf(y1f, 0.f), (float)(HH - 1));
        int p00 = Y0 * WW + X0, p01 = Y1 * WW + X0;
        int p10 = Y0 * WW + X1, p11 = Y1 * WW + X1;
        int c0 = lane * 2;
        const float* f0 = features + (size_t)(b * CC + c0) * (HH * WW);
        const float* f1 = f0 + HH * WW;
        float v0 = w00 * f0[p00] + w01 * f0[p01] + w10 * f0[p10] + w11 * f0[p11];
        float v1 = w00 * f1[p00] + w01 * f1[p01] + w10 * f1[p10] + w11 * f1[p11];
        unsigned int pk = (unsigned int)f2bf_bits(v0) | ((unsigned int)f2bf_bits(v1) << 16);
        *(unsigned int*)(x0p + (size_t)idx * 256 + c0) = pk;
        unsigned int pk2 = 0;
        if (lane == 0)
            pk2 = (unsigned int)f2bf_bits(bx) | ((unsigned int)f2bf_bits(by) << 16);
        *(unsigned int*)(x0p + (size_t)idx * 256 + 128 + c0) = pk2;
    } else {
        int idx = bid - 1024;               // 0..1791
        int m   = idx >> 6;                 // matrix 0..27
        int sub = idx & 63;
        int bx = sub & 7, by = sub >> 3;
        const float* S; int R;
        if (m < 2)       { S = w_first + (size_t)m * 130 * 256; R = 130; }
        else if (m < 26) { S = w_mid + (size_t)(m - 2) * 65536; R = 256; }
        else             { S = w_last + (size_t)(m - 26) * 65536; R = 256; }
        bf16* D = wT + (size_t)m * 65536;
        int tx = t & 31, ty = t >> 5;
        int c0 = bx * 32, r0 = by * 32;
        #pragma unroll
        for (int k = 0; k < 4; ++k) {
            int r = r0 + ty + 8 * k;
            tbuf[ty + 8 * k][tx] = (r < R) ? S[(size_t)r * 256 + c0 + tx] : 0.f;
        }
        __syncthreads();
        #pragma unroll
        for (int k = 0; k < 4; ++k) {
            int c = c0 + ty + 8 * k;
            D[(size_t)c * 256 + r0 + tx] = __float2bfloat16(tbuf[tx][ty + 8 * k]);
        }
    }
}

// ======== S: x = combine(gprev + Y0..Y3 + b1 + b2 [+res][relu]) ; [g1|g2T] = x @ wcat ========
// single-phase: stage ALL weights (64 KB, 4 K-planes) + full A tile (16 KB), 1 barrier, 32 MFMA.
// 512 blocks 1-D (XCD-swizzled): lin = ct(4) + 4*rt(128). XCD x owns rows 512x..512x+511.
__global__ __launch_bounds__(256, 2) void s_kernel(const bf16* __restrict__ gprev,
                                                   const bf16* __restrict__ Yb,
                                                   const float* __restrict__ bias1,
                                                   const float* __restrict__ bias2,
                                                   const bf16* __restrict__ res,
                                                   int relu,
                                                   const bf16* __restrict__ wcat,
                                                   bf16* __restrict__ xR,
                                                   bf16* __restrict__ g1out,
                                                   bf16* __restrict__ g2T) {
    __shared__ char lds[81920];         // Bl: 4 planes x 16 KB @0 ; Al: 4 planes x 4 KB @65536
    char* Bl = lds;
    char* Al = lds + 65536;
    int tid = threadIdx.x;
    int bid = blockIdx.x;
    int lin = (bid & 7) * 64 + (bid >> 3);
    int ct = lin & 3, rt = lin >> 2;
    int lane = tid & 63, w = tid >> 6;
    int wr = w >> 1, wc = w & 1;       // wave: 16 rows x 64 outfeats
    int row16 = lane & 15, kg = lane >> 4;

    // ---- stage all weights: plane p holds K-chunk p (64 wide), rows 0..127, 128B rows swizzled ----
    #pragma unroll
    for (int rnd = 0; rnd < 16; ++rnd) {
        int plane = rnd >> 2;
        int dp = (rnd & 3) * 4096 + tid * 16;   // within-plane byte
        int row = dp >> 7;                       // 0..127
        int cb = dp & 127;
        int sc = (cb ^ ((row & 7) << 4)) >> 1;
        __builtin_amdgcn_global_load_lds(
            (const __attribute__((address_space(1))) void*)(wcat + (size_t)(ct * 128 + row) * 256 + plane * 64 + sc),
            (__attribute__((address_space(3))) void*)(Bl + plane * 16384 + (rnd & 3) * 4096 + (w << 10)),
            16, 0, 0);
    }

    // ---- A combine: 4 planes, per thread one short8 per plane ----
    {
        int arow = tid >> 3;                 // 0..31
        int acb  = (tid * 16) & 127;
        int ridx = rt * 32 + arow;
        int awb  = arow * 128 + (acb ^ ((arow & 7) << 4));
        #pragma unroll
        for (int rnd = 0; rnd < 4; ++rnd) {
            int gcol = rnd * 64 + (acb >> 1);
            size_t off = (size_t)ridx * 256 + gcol;
            short8 pk;
            if (Yb) {
                short8 gv  = *(const short8*)(gprev + off);
                float fv[8];
                #pragma unroll
                for (int j = 0; j < 8; ++j) fv[j] = bf2f((unsigned short)gv[j]);
                #pragma unroll
                for (int p = 0; p < 4; ++p) {
                    short8 yv = *(const short8*)(Yb + (size_t)p * YSTR + off);
                    #pragma unroll
                    for (int j = 0; j < 8; ++j) fv[j] += bf2f((unsigned short)yv[j]);
                }
                short8 rv = {};
                if (res) rv = *(const short8*)(res + off);
                #pragma unroll
                for (int j = 0; j < 8; ++j) {
                    float f = fv[j] + bias1[gcol + j] + bias2[gcol + j];
                    if (res)  f += bf2f((unsigned short)rv[j]);
                    if (relu) f = fmaxf(f, 0.f);
                    pk[j] = (short)f2bf_bits(f);
                }
            } else {
                pk = *(const short8*)(gprev + off);
            }
            if (ct == 0) *(short8*)(xR + off) = pk;
            *(short8*)(Al + rnd * 4096 + awb) = pk;
        }
    }

    asm volatile("s_waitcnt vmcnt(0) lgkmcnt(0)" ::: "memory");
    __builtin_amdgcn_s_barrier();

    f32x4 acc[4] = {};
    int arow = wr * 16 + row16;
    #pragma unroll
    for (int kk = 0; kk < 8; ++kk) {
        int plane = kk >> 1, kk2 = kk & 1;
        int kof = kk2 * 64 + kg * 16;
        short8 a = *(const short8*)(Al + plane * 4096 + arow * 128 + (kof ^ ((arow & 7) << 4)));
        #pragma unroll
        for (int nf = 0; nf < 4; ++nf) {
            int fr = wc * 64 + nf * 16 + row16;
            short8 bfr = *(const short8*)(Bl + plane * 16384 + fr * 128 + (kof ^ ((fr & 7) << 4)));
            acc[nf] = __builtin_amdgcn_mfma_f32_16x16x32_bf16(a, bfr, acc[nf], 0, 0, 0);
        }
    }

    int cbase = ct * 128 + wc * 64;
    int rb = rt * 32 + wr * 16 + kg * 4;
    if (cbase < 256) {
        #pragma unroll
        for (int nf = 0; nf < 4; ++nf) {
            int c = cbase + nf * 16 + row16;
            #pragma unroll
            for (int j = 0; j < 4; ++j)
                *reinterpret_cast<unsigned short*>(&g1out[(size_t)(rb + j) * 256 + c]) = f2bf_bits(acc[nf][j]);
        }
    } else {
        #pragma unroll
        for (int nf = 0; nf < 4; ++nf) {
            int c = cbase - 256 + nf * 16 + row16;
            ushort4v pk;
            #pragma unroll
            for (int j = 0; j < 4; ++j) pk[j] = f2bf_bits(acc[nf][j]);
            *(ushort4v*)(g2T + (size_t)c * 4096 + rb) = pk;
        }
    }
}

// ======== B: Y[ks] = adj[:, ks quarter] @ g2 — BM=128, BN=64, split-K=4 ========
// double-buffered counted-vmcnt(6) pipeline (2 x 24 KB LDS). [R8-measured-best variant]
// 512 blocks, PRODUCER-ALIGNED XCD decode: XCD x owns rows 512x..512x+511 (all 4 ks partials),
// matching s_kernel's consumer XCD x rows -> Y stays in XCD-local L2 across the s/adjb boundary.
// lin = (bid&7)*64 + (bid>>3); ct=lin&3, ks=(lin>>2)&3, rtl=(lin>>4)&3, xcd=lin>>6;
// rt = (xcd&3)*4 + rtl, b = xcd>>2.
__global__ __launch_bounds__(256, 2) void adjb_kernel(const bf16* __restrict__ adjB,
                                                      const bf16* __restrict__ g2T,
                                                      bf16* __restrict__ Ybase) {
    __shared__ char lds[49152];         // buf i @ i*24576: A 16 KB, B 8 KB @ +16384
    int tid = threadIdx.x;
    int bid = blockIdx.x;
    int lin = (bid & 7) * 64 + (bid >> 3);
    int ct  = lin & 3;
    int ks  = (lin >> 2) & 3;
    int rtl = (lin >> 4) & 3;
    int xcd = lin >> 6;
    int rt  = (xcd & 3) * 4 + rtl;
    int b   = xcd >> 2;
    const bf16* Aadj = adjB + (size_t)b * NN * NN + (size_t)(rt * 128) * NN + ks * 512;
    const bf16* Bg   = g2T + (size_t)(ct * 64) * 4096 + b * NN + ks * 512;
    bf16* Yo = Ybase + (size_t)ks * YSTR;
    int lane = tid & 63, w = tid >> 6;
    int wr = w >> 1, wc = w & 1;       // wave tile: 64 rows x 32 cols
    int row16 = lane & 15, kg = lane >> 4;
    f32x4 acc[4][2] = {};

    #define STAGE(BUF, IT)                                                                \
        {                                                                                 \
            int k0 = (IT) * 64;                                                           \
            _Pragma("unroll")                                                             \
            for (int rnd = 0; rnd < 4; ++rnd) {                                           \
                int d = tid * 16 + rnd * 4096;                                            \
                int row = d >> 7, cb = d & 127;                                           \
                int sc = (cb ^ ((row & 7) << 4)) >> 1;                                    \
                __builtin_amdgcn_global_load_lds(                                         \
                    (const __attribute__((address_space(1))) void*)(Aadj + (size_t)row * NN + k0 + sc), \
                    (__attribute__((address_space(3))) void*)(lds + (BUF) * 24576 + rnd * 4096 + (w << 10)), \
                    16, 0, 0);                                                            \
            }                                                                             \
            _Pragma("unroll")                                                             \
            for (int rnd = 0; rnd < 2; ++rnd) {                                           \
                int d = tid * 16 + rnd * 4096;                                            \
                int row = d >> 7, cb = d & 127;                                           \
                int sc = (cb ^ ((row & 7) << 4)) >> 1;                                    \
                __builtin_amdgcn_global_load_lds(                                         \
                    (const __attribute__((address_space(1))) void*)(Bg + (size_t)row * 4096 + k0 + sc), \
                    (__attribute__((address_space(3))) void*)(lds + (BUF) * 24576 + 16384 + rnd * 4096 + (w << 10)), \
                    16, 0, 0);                                                            \
            }                                                                             \
        }

    #define MFMA_STEP(BUF)                                                                \
        _Pragma("unroll")                                                                 \
        for (int kk = 0; kk < 2; ++kk) {                                                  \
            short8 a[4], bfr[2];                                                          \
            _Pragma("unroll")                                                             \
            for (int mf = 0; mf < 4; ++mf) {                                              \
                int row = wr * 64 + mf * 16 + row16;                                      \
                a[mf] = *(const short8*)(lds + (BUF) * 24576 + row * 128 +                \
                          (((kk * 64) + kg * 16) ^ ((row & 7) << 4)));                    \
            }                                                                             \
            _Pragma("unroll")                                                             \
            for (int nf = 0; nf < 2; ++nf) {                                              \
                int fr = wc * 32 + nf * 16 + row16;                                       \
                bfr[nf] = *(const short8*)(lds + (BUF) * 24576 + 16384 + fr * 128 +       \
                          (((kk * 64) + kg * 16) ^ ((fr & 7) << 4)));                     \
            }                                                                             \
            _Pragma("unroll")                                                             \
            for (int mf = 0; mf < 4; ++mf)                                                \
                _Pragma("unroll")                                                         \
                for (int nf = 0; nf < 2; ++nf)                                            \
                    acc[mf][nf] = __builtin_amdgcn_mfma_f32_16x16x32_bf16(a[mf], bfr[nf], acc[mf][nf], 0, 0, 0); \
        }

    #define ITER_MID(CURBUF, NXTBUF, NXTIT)                                               \
        STAGE(NXTBUF, NXTIT);                                                             \
        asm volatile("s_waitcnt vmcnt(6)" ::: "memory");                                  \
        __builtin_amdgcn_s_barrier();                                                     \
        MFMA_STEP(CURBUF);                                                                \
        __builtin_amdgcn_s_barrier();

    STAGE(0, 0);
    ITER_MID(0, 1, 1)       // it 0
    ITER_MID(1, 0, 2)       // it 1
    ITER_MID(0, 1, 3)       // it 2
    ITER_MID(1, 0, 4)       // it 3
    ITER_MID(0, 1, 5)       // it 4
    ITER_MID(1, 0, 6)       // it 5
    ITER_MID(0, 1, 7)       // it 6
    // it 7 (no further stage)
    asm volatile("s_waitcnt vmcnt(0)" ::: "memory");
    __builtin_amdgcn_s_barrier();
    MFMA_STEP(1);

    #pragma unroll
    for (int mf = 0; mf < 4; ++mf) {
        #pragma unroll
        for (int nf = 0; nf < 2; ++nf) {
            int c  = ct * 64 + wc * 32 + nf * 16 + row16;
            int r0 = b * NN + rt * 128 + wr * 64 + mf * 16 + kg * 4;
            #pragma unroll
            for (int j = 0; j < 4; ++j)
                *reinterpret_cast<unsigned short*>(&Yo[(size_t)(r0 + j) * 256 + c]) = f2bf_bits(acc[mf][nf][j]);
        }
    }
    #undef STAGE
    #undef MFMA_STEP
    #undef ITER_MID
}

// ======== head: z = g1 + ΣY + b_last ; gcn_pred = z@w_fc + b_fc ; outputs; zero lap accumulators ========
// 64 blocks x 256 threads: 4 threads per row, 64 dims each, quad shfl-reduce.
__global__ void head_kernel(const bf16* __restrict__ g1, const bf16* __restrict__ Yb,
                            const float* __restrict__ b_last,
                            const float* __restrict__ w_fc, const float* __restrict__ b_fc,
                            const float* __restrict__ base_point, const float* __restrict__ point_mask,
                            float* __restrict__ out, float* __restrict__ dpts) {
    if (blockIdx.x == 0 && threadIdx.x < 2)
        out[4 * BB * NN + threadIdx.x] = 0.f;
    int t = threadIdx.x;
    int row = blockIdx.x * 64 + (t >> 2);
    int q = t & 3;
    float s0 = 0.f, s1 = 0.f;
    #pragma unroll
    for (int d8 = 0; d8 < 64; d8 += 8) {
        int d = q * 64 + d8;
        size_t off = (size_t)row * 256 + d;
        short8 a = *(const short8*)(g1 + off);
        float zv[8];
        #pragma unroll
        for (int j = 0; j < 8; ++j) zv[j] = bf2f((unsigned short)a[j]);
        #pragma unroll
        for (int p = 0; p < 4; ++p) {
            short8 yv = *(const short8*)(Yb + (size_t)p * YSTR + off);
            #pragma unroll
            for (int j = 0; j < 8; ++j) zv[j] += bf2f((unsigned short)yv[j]);
        }
        #pragma unroll
        for (int j = 0; j < 8; ++j) {
            float z = zv[j] + b_last[d + j] + b_last[256 + d + j];
            s0 += z * w_fc[(d + j) * 2 + 0];
            s1 += z * w_fc[(d + j) * 2 + 1];
        }
    }
    s0 += __shfl_xor(s0, 1); s0 += __shfl_xor(s0, 2);
    s1 += __shfl_xor(s1, 1); s1 += __shfl_xor(s1, 2);
    if (q == 0) {
        s0 += b_fc[0];
        s1 += b_fc[1];
        float m  = point_mask[row];
        float p0 = base_point[row * 2 + 0] + s0 * m;
        float p1 = base_point[row * 2 + 1] + s1 * m;
        out[row * 2 + 0] = p0;
        out[row * 2 + 1] = p1;
        out[2 * BB * NN + row * 2 + 0] = s0;
        out[2 * BB * NN + row * 2 + 1] = s1;
        dpts[row * 2 + 0] = s0 * m;
        dpts[row * 2 + 1] = s1 * m;
    }
}

// ======== lap: t = sqrt(|d - adj@d|^2 + 1e-10) per row; block-reduce; atomicAdd mean ========
__global__ void lap_rows(const bf16* __restrict__ adjB, const float* __restrict__ dpts,
                         float* __restrict__ outlap) {
    __shared__ float sd[4];
    int w    = threadIdx.x >> 6;
    int lane = threadIdx.x & 63;
    int row  = blockIdx.x * 4 + w;
    int b = row >> 11, n = row & 2047;
    const bf16* ar = adjB + (size_t)b * NN * NN + (size_t)n * NN;
    const float* db = dpts + (size_t)b * NN * 2;
    float s0 = 0.f, s1 = 0.f;
    for (int k4 = 0; k4 < 4; ++k4) {
        int k = k4 * 512 + lane * 8;
        short8 av = *(const short8*)(ar + k);
        #pragma unroll
        for (int j = 0; j < 8; ++j) {
            float a = bf2f((unsigned short)av[j]);
            float2 dv = *(const float2*)(db + (k + j) * 2);
            s0 += a * dv.x;
            s1 += a * dv.y;
        }
    }
    for (int off = 32; off; off >>= 1) {
        s0 += __shfl_xor(s0, off);
        s1 += __shfl_xor(s1, off);
    }
    if (lane == 0) {
        float e0 = dpts[(size_t)row * 2 + 0] - s0;
        float e1 = dpts[(size_t)row * 2 + 1] - s1;
        sd[w] = sqrtf(e0 * e0 + e1 * e1 + 1e-10f);
    }
    __syncthreads();
    if (threadIdx.x == 0) {
        float s = (sd[0] + sd[1] + sd[2] + sd[3]) * (1.f / (float)NN);
        atomicAdd(&outlap[b], s);
    }
}

extern "C" void kernel_launch(void* const* d_in, const int* in_sizes, int n_in,
                              void* d_out, int out_size, void* d_ws, size_t ws_size,
                              hipStream_t stream) {
    const float* features   = (const float*)d_in[0];
    const float* base_point = (const float*)d_in[1];
    const float* adj        = (const float*)d_in[2];
    const float* point_mask = (const float*)d_in[3];
    const float* w_first    = (const float*)d_in[4];
    const float* b_first    = (const float*)d_in[5];
    const float* w_mid      = (const float*)d_in[6];
    const float* b_mid      = (const float*)d_in[7];
    const float* w_last     = (const float*)d_in[8];
    const float* b_last     = (const float*)d_in[9];
    const float* w_fc       = (const float*)d_in[10];
    const float* b_fc       = (const float*)d_in[11];
    float* out = (float*)d_out;
    char* W = (char*)d_ws;

    bf16* adjB   = (bf16*)W;                          // 16.78 MB
    bf16* wT     = (bf16*)(W + 16777216);             // 3.67 MB
    bf16* x0p    = (bf16*)(W + 20447232);
    bf16* g1b[2] = { (bf16*)(W + 22544384), (bf16*)(W + 24641536) };
    bf16* g2T    = (bf16*)(W + 26738688);
    bf16* Yb     = (bf16*)(W + 28835840);             // 4 partials x 2 MB
    bf16* xsl[2] = { (bf16*)(W + 45613056), (bf16*)(W + 47710208) };
    bf16* xscr   = (bf16*)(W + 49807360);
    float* dpts  = (float*)(W + 51904512);

    conv_kernel<<<2048, 256, 0, stream>>>(adj, adjB);
    misc_kernel<<<2816, 256, 0, stream>>>(features, base_point, x0p,
                                          w_first, w_mid, w_last, wT);

    // L0
    s_kernel<<<512, 256, 0, stream>>>(x0p, nullptr, nullptr, nullptr, nullptr, 0,
                                      wT, xscr, g1b[0], g2T);
    adjb_kernel<<<512, 256, 0, stream>>>(adjB, g2T, Yb);

    for (int k = 1; k < 14; ++k) {
        const float *bb1, *bb2;
        const bf16* resp = nullptr;
        bf16* xw;
        int rl;
        if (k == 1) {
            bb1 = b_first; bb2 = b_first + 256; rl = 0; xw = xsl[0];
        } else if ((k & 1) == 0) {
            int m = (k - 2) / 2;
            bb1 = b_mid + (size_t)m * 1024; bb2 = bb1 + 256;
            rl = 1; xw = xscr;
        } else {
            int m = (k - 3) / 2;
            bb1 = b_mid + (size_t)m * 1024 + 512; bb2 = bb1 + 256;
            rl = 1;
            resp = xsl[m & 1];
            xw   = xsl[((k - 1) / 2) & 1];
        }
        s_kernel<<<512, 256, 0, stream>>>(g1b[(k - 1) & 1], Yb, bb1, bb2, resp, rl,
                                          wT + (size_t)2 * k * 65536, xw, g1b[k & 1], g2T);
        adjb_kernel<<<512, 256, 0, stream>>>(adjB, g2T, Yb);
    }

    head_kernel<<<64, 256, 0, stream>>>(g1b[1], Yb, b_last, w_fc, b_fc,
                                        base_point, point_mask, out, dpts);
    lap_rows<<<1024, 256, 0, stream>>>(adjB, dpts, out + 4 * BB * NN);
}